// Round 2
// baseline (3572.676 us; speedup 1.0000x reference)
//
#include <hip/hip_runtime.h>
#include <hip/hip_bf16.h>

#define B_SZ 4
#define L_SEQ 2048
#define D_MODEL 1024
#define D_INNER 2048
#define D_STATE 16
#define DT_RANK 64
#define NROW (B_SZ * L_SEQ)   // 8192

// ---------------------------------------------------------------------------
// Generic tiled fp32 GEMM: C[M,N] = A[M,K] * B[K,N], row-major with strides.
// 64x64 tile, 256 threads, 4x4 micro-tile per thread.
// ---------------------------------------------------------------------------
__global__ __launch_bounds__(256) void gemm_f32(
    const float* __restrict__ A, const float* __restrict__ B, float* __restrict__ C,
    int M, int N, int K, int lda, int ldb, int ldc)
{
    __shared__ __align__(16) float As[16][68];  // [k][m]
    __shared__ __align__(16) float Bs[16][68];  // [k][n]
    const int tid = threadIdx.x;
    const int tx = tid & 15, ty = tid >> 4;
    const int m0 = blockIdx.y * 64, n0 = blockIdx.x * 64;

    float c[4][4] = {};

    for (int k0 = 0; k0 < K; k0 += 16) {
        {
            const int ka = tid & 15, ma = tid >> 4;
            #pragma unroll
            for (int p = 0; p < 4; ++p) {
                const int m = ma + p * 16;
                float v = 0.f;
                if (m0 + m < M && k0 + ka < K) v = A[(size_t)(m0 + m) * lda + k0 + ka];
                As[ka][m] = v;
            }
        }
        {
            const int nb = tid & 63, kb = tid >> 6;
            #pragma unroll
            for (int p = 0; p < 4; ++p) {
                const int k = kb + p * 4;
                float v = 0.f;
                if (k0 + k < K && n0 + nb < N) v = B[(size_t)(k0 + k) * ldb + n0 + nb];
                Bs[k][nb] = v;
            }
        }
        __syncthreads();
        #pragma unroll
        for (int kk = 0; kk < 16; ++kk) {
            const float4 av = *reinterpret_cast<const float4*>(&As[kk][ty * 4]);
            const float4 bv = *reinterpret_cast<const float4*>(&Bs[kk][tx * 4]);
            const float a[4] = {av.x, av.y, av.z, av.w};
            const float b[4] = {bv.x, bv.y, bv.z, bv.w};
            #pragma unroll
            for (int i = 0; i < 4; ++i)
                #pragma unroll
                for (int j = 0; j < 4; ++j)
                    c[i][j] = fmaf(a[i], b[j], c[i][j]);
        }
        __syncthreads();
    }

    #pragma unroll
    for (int i = 0; i < 4; ++i) {
        const int m = m0 + ty * 4 + i;
        if (m >= M) continue;
        #pragma unroll
        for (int j = 0; j < 4; ++j) {
            const int n = n0 + tx * 4 + j;
            if (n < N) C[(size_t)m * ldc + n] = c[i][j];
        }
    }
}

// ---------------------------------------------------------------------------
// Depthwise conv (taps x[t-6..t-3] per reference's (6,3) padding + [:L]) +
// bias + SiLU.  x read from the x-half of xz (row stride 4096).
// ---------------------------------------------------------------------------
__global__ __launch_bounds__(256) void conv_silu_kernel(
    const float* __restrict__ xz, const float* __restrict__ conv_w,
    const float* __restrict__ conv_b, float* __restrict__ x_bld)
{
    const int idx = blockIdx.x * 256 + threadIdx.x;
    if (idx >= B_SZ * L_SEQ * D_INNER) return;
    const int d = idx & (D_INNER - 1);
    const int t = (idx >> 11) & (L_SEQ - 1);
    const int b = idx >> 22;

    const float4 w = *reinterpret_cast<const float4*>(&conv_w[d * 4]);
    const float wk[4] = {w.x, w.y, w.z, w.w};
    float acc = conv_b[d];
    const size_t rowbase = (size_t)b * L_SEQ * 4096 + d;  // xz[b][0][d]
    #pragma unroll
    for (int k = 0; k < 4; ++k) {
        const int tt = t - 6 + k;
        if (tt >= 0) acc = fmaf(wk[k], xz[rowbase + (size_t)tt * 4096], acc);
    }
    const float s = acc / (1.f + __expf(-acc));  // SiLU
    x_bld[idx] = s;
}

// ---------------------------------------------------------------------------
// delta[m, d] = softplus( sum_r x_dbl[m, r] * W[r, d]  +  2 * bias[d] )
// (the reference adds dt_proj_b twice). delta is written over the x-half of
// xz (row stride 4096) — that region is dead after the conv consumed it.
// ---------------------------------------------------------------------------
__global__ __launch_bounds__(256) void dt_softplus_kernel(
    const float* __restrict__ x_dbl, const float* __restrict__ W,
    const float* __restrict__ bias, float* __restrict__ delta_xz)
{
    __shared__ float a[16][64];
    const int tid = threadIdx.x;
    const int m0 = blockIdx.y * 16;
    const int d = blockIdx.x * 256 + tid;

    {
        const int r = tid & 63, i = tid >> 6;  // 4 rows per pass
        #pragma unroll
        for (int p = 0; p < 4; ++p)
            a[i + p * 4][r] = x_dbl[(size_t)(m0 + i + p * 4) * 96 + r];
    }
    __syncthreads();

    float acc[16] = {};
    for (int r = 0; r < 64; ++r) {
        const float w = W[(size_t)r * D_INNER + d];
        #pragma unroll
        for (int mi = 0; mi < 16; ++mi) acc[mi] = fmaf(a[mi][r], w, acc[mi]);
    }
    const float b2 = 2.0f * bias[d];
    #pragma unroll
    for (int mi = 0; mi < 16; ++mi) {
        const float v = acc[mi] + b2;
        const float sp = (v > 20.0f) ? v : log1pf(__expf(v));
        delta_xz[(size_t)(m0 + mi) * 4096 + d] = sp;  // x-half of xz
    }
}

// ---------------------------------------------------------------------------
// Selective scan. One thread per (b, d, n): 131072 threads. Lane group of 16
// covers the 16 states of one channel; __shfl_xor reduces y = sum_n h*C.
// delta lives in the x-half of xz; y overwrites the same slot (read-then-
// write, dataflow ordered). z is the upper half of each xz row.
// Fused epilogue: y = (scan_y + u*D_skip) * silu(z).
// NOTE: xz deliberately NOT __restrict__ (delta read + y write alias).
// ---------------------------------------------------------------------------
__global__ __launch_bounds__(256) void scan_kernel(
    float* xz, const float* __restrict__ u_,
    const float* __restrict__ x_dbl, const float* __restrict__ A_log,
    const float* __restrict__ D_skip)
{
    const int g = blockIdx.x * 256 + threadIdx.x;  // 0 .. 131071
    const int n = g & 15;
    const int d = (g >> 4) & (D_INNER - 1);
    const int b = g >> 15;

    const float A = -__expf(A_log[d * D_STATE + n]);
    const float Dd = D_skip[d];

    const size_t base2048 = (size_t)b * L_SEQ * D_INNER + d;
    const size_t base96   = (size_t)b * L_SEQ * 96;
    const size_t base4096 = (size_t)b * L_SEQ * 4096;

    float h = 0.f;
    #pragma unroll 4
    for (int t = 0; t < L_SEQ; ++t) {
        const float dv = xz[base4096 + (size_t)t * 4096 + d];          // delta
        const float uv = u_[base2048 + (size_t)t * D_INNER];
        const float Bv = x_dbl[base96 + (size_t)t * 96 + DT_RANK + n];
        const float Cv = x_dbl[base96 + (size_t)t * 96 + DT_RANK + D_STATE + n];

        const float dA = __expf(dv * A);
        const float du = dv * uv;
        h = fmaf(h, dA, du * Bv);
        float c = h * Cv;
        c += __shfl_xor(c, 1);
        c += __shfl_xor(c, 2);
        c += __shfl_xor(c, 4);
        c += __shfl_xor(c, 8);
        if (n == 0) {
            const float zv = xz[base4096 + (size_t)t * 4096 + D_INNER + d];
            const float sig = 1.f / (1.f + __expf(-zv));
            const float yv = (c + uv * Dd) * (zv * sig);
            xz[base4096 + (size_t)t * 4096 + d] = yv;                  // y over delta
        }
    }
}

// ---------------------------------------------------------------------------
extern "C" void kernel_launch(void* const* d_in, const int* in_sizes, int n_in,
                              void* d_out, int out_size, void* d_ws, size_t ws_size,
                              hipStream_t stream)
{
    const float* hs         = (const float*)d_in[0];
    const float* in_proj_w  = (const float*)d_in[1];
    const float* conv_w     = (const float*)d_in[2];
    const float* conv_b     = (const float*)d_in[3];
    const float* x_proj_w   = (const float*)d_in[4];
    const float* dt_proj_w  = (const float*)d_in[5];
    const float* dt_proj_b  = (const float*)d_in[6];
    const float* A_log      = (const float*)d_in[7];
    const float* D_skip     = (const float*)d_in[8];
    const float* out_proj_w = (const float*)d_in[9];
    float* out = (float*)d_out;

    // Workspace layout (fp32 elems):
    //   xz    : NROW*4096 = 33,554,432  (134.2 MB)  x-half later reused for delta, then y
    //   x_bld : NROW*2048 = 16,777,216  ( 67.1 MB)
    //   x_dbl : NROW*96   =    786,432  (  3.1 MB)
    // total 204.5 MB
    float* ws    = (float*)d_ws;
    float* xz    = ws;
    float* x_bld = xz + (size_t)NROW * 4096;
    float* x_dbl = x_bld + (size_t)NROW * 2048;

    // K1: xz = hs @ in_proj_w        [8192,1024] @ [1024,4096]
    {
        dim3 grid(4096 / 64, NROW / 64);
        hipLaunchKernelGGL(gemm_f32, grid, dim3(256), 0, stream,
                           hs, in_proj_w, xz, NROW, 4096, D_MODEL, D_MODEL, 4096, 4096);
    }
    // K2: depthwise conv + bias + silu -> x_bld
    {
        const int total = B_SZ * L_SEQ * D_INNER;
        hipLaunchKernelGGL(conv_silu_kernel, dim3((total + 255) / 256), dim3(256), 0, stream,
                           xz, conv_w, conv_b, x_bld);
    }
    // K3: x_dbl = x_bld @ x_proj_w   [8192,2048] @ [2048,96]
    {
        dim3 grid((96 + 63) / 64, NROW / 64);
        hipLaunchKernelGGL(gemm_f32, grid, dim3(256), 0, stream,
                           x_bld, x_proj_w, x_dbl, NROW, 96, D_INNER, D_INNER, 96, 96);
    }
    // K4: delta = softplus(dt_low @ dt_proj_w + 2*dt_proj_b) -> x-half of xz
    {
        dim3 grid(D_INNER / 256, NROW / 16);
        hipLaunchKernelGGL(dt_softplus_kernel, grid, dim3(256), 0, stream,
                           x_dbl, dt_proj_w, dt_proj_b, xz);
    }
    // K5: selective scan + skip + gate; y overwrites delta in x-half of xz
    {
        hipLaunchKernelGGL(scan_kernel, dim3((B_SZ * D_INNER * D_STATE) / 256), dim3(256), 0, stream,
                           xz, x_bld, x_dbl, A_log, D_skip);
    }
    // K6: out = y @ out_proj_w       [8192,2048(stride 4096)] @ [2048,1024]
    {
        dim3 grid(D_MODEL / 64, NROW / 64);
        hipLaunchKernelGGL(gemm_f32, grid, dim3(256), 0, stream,
                           xz, out_proj_w, out, NROW, D_MODEL, D_INNER, 4096, D_MODEL, D_MODEL);
    }
}

// Round 3
// 2541.338 us; speedup vs baseline: 1.4058x; 1.4058x over previous
//
#include <hip/hip_runtime.h>
#include <hip/hip_bf16.h>

#define B_SZ 4
#define L_SEQ 2048
#define D_MODEL 1024
#define D_INNER 2048
#define D_STATE 16
#define DT_RANK 64
#define NROW (B_SZ * L_SEQ)   // 8192
#define NCHUNK 16
#define CHUNK (L_SEQ / NCHUNK)  // 128

// ---------------------------------------------------------------------------
// Generic tiled fp32 GEMM: C[M,N] = A[M,K] * B[K,N], row-major with strides.
// ---------------------------------------------------------------------------
__global__ __launch_bounds__(256) void gemm_f32(
    const float* __restrict__ A, const float* __restrict__ B, float* __restrict__ C,
    int M, int N, int K, int lda, int ldb, int ldc)
{
    __shared__ __align__(16) float As[16][68];  // [k][m]
    __shared__ __align__(16) float Bs[16][68];  // [k][n]
    const int tid = threadIdx.x;
    const int tx = tid & 15, ty = tid >> 4;
    const int m0 = blockIdx.y * 64, n0 = blockIdx.x * 64;

    float c[4][4] = {};

    for (int k0 = 0; k0 < K; k0 += 16) {
        {
            const int ka = tid & 15, ma = tid >> 4;
            #pragma unroll
            for (int p = 0; p < 4; ++p) {
                const int m = ma + p * 16;
                float v = 0.f;
                if (m0 + m < M && k0 + ka < K) v = A[(size_t)(m0 + m) * lda + k0 + ka];
                As[ka][m] = v;
            }
        }
        {
            const int nb = tid & 63, kb = tid >> 6;
            #pragma unroll
            for (int p = 0; p < 4; ++p) {
                const int k = kb + p * 4;
                float v = 0.f;
                if (k0 + k < K && n0 + nb < N) v = B[(size_t)(k0 + k) * ldb + n0 + nb];
                Bs[k][nb] = v;
            }
        }
        __syncthreads();
        #pragma unroll
        for (int kk = 0; kk < 16; ++kk) {
            const float4 av = *reinterpret_cast<const float4*>(&As[kk][ty * 4]);
            const float4 bv = *reinterpret_cast<const float4*>(&Bs[kk][tx * 4]);
            const float a[4] = {av.x, av.y, av.z, av.w};
            const float b[4] = {bv.x, bv.y, bv.z, bv.w};
            #pragma unroll
            for (int i = 0; i < 4; ++i)
                #pragma unroll
                for (int j = 0; j < 4; ++j)
                    c[i][j] = fmaf(a[i], b[j], c[i][j]);
        }
        __syncthreads();
    }

    #pragma unroll
    for (int i = 0; i < 4; ++i) {
        const int m = m0 + ty * 4 + i;
        if (m >= M) continue;
        #pragma unroll
        for (int j = 0; j < 4; ++j) {
            const int n = n0 + tx * 4 + j;
            if (n < N) C[(size_t)m * ldc + n] = c[i][j];
        }
    }
}

// ---------------------------------------------------------------------------
// Depthwise conv (taps x[t-6..t-3]) + bias + SiLU.
// ---------------------------------------------------------------------------
__global__ __launch_bounds__(256) void conv_silu_kernel(
    const float* __restrict__ xz, const float* __restrict__ conv_w,
    const float* __restrict__ conv_b, float* __restrict__ x_bld)
{
    const int idx = blockIdx.x * 256 + threadIdx.x;
    if (idx >= B_SZ * L_SEQ * D_INNER) return;
    const int d = idx & (D_INNER - 1);
    const int t = (idx >> 11) & (L_SEQ - 1);
    const int b = idx >> 22;

    const float4 w = *reinterpret_cast<const float4*>(&conv_w[d * 4]);
    const float wk[4] = {w.x, w.y, w.z, w.w};
    float acc = conv_b[d];
    const size_t rowbase = (size_t)b * L_SEQ * 4096 + d;
    #pragma unroll
    for (int k = 0; k < 4; ++k) {
        const int tt = t - 6 + k;
        if (tt >= 0) acc = fmaf(wk[k], xz[rowbase + (size_t)tt * 4096], acc);
    }
    const float s = acc / (1.f + __expf(-acc));
    x_bld[idx] = s;
}

// ---------------------------------------------------------------------------
// delta = softplus(dt_low @ dt_proj_w + 2*bias) -> x-half of xz (stride 4096)
// ---------------------------------------------------------------------------
__global__ __launch_bounds__(256) void dt_softplus_kernel(
    const float* __restrict__ x_dbl, const float* __restrict__ W,
    const float* __restrict__ bias, float* __restrict__ delta_xz)
{
    __shared__ float a[16][64];
    const int tid = threadIdx.x;
    const int m0 = blockIdx.y * 16;
    const int d = blockIdx.x * 256 + tid;

    {
        const int r = tid & 63, i = tid >> 6;
        #pragma unroll
        for (int p = 0; p < 4; ++p)
            a[i + p * 4][r] = x_dbl[(size_t)(m0 + i + p * 4) * 96 + r];
    }
    __syncthreads();

    float acc[16] = {};
    for (int r = 0; r < 64; ++r) {
        const float w = W[(size_t)r * D_INNER + d];
        #pragma unroll
        for (int mi = 0; mi < 16; ++mi) acc[mi] = fmaf(a[mi][r], w, acc[mi]);
    }
    const float b2 = 2.0f * bias[d];
    #pragma unroll
    for (int mi = 0; mi < 16; ++mi) {
        const float v = acc[mi] + b2;
        const float sp = (v > 20.0f) ? v : log1pf(__expf(v));
        delta_xz[(size_t)(m0 + mi) * 4096 + d] = sp;
    }
}

// ---------------------------------------------------------------------------
// Chunked parallel scan. h[t] = a[t]*h[t-1] + b[t] is affine, so:
// Pass 1: per (b,d,n,chunk) local scan from 0 + cumprod of a. 2M threads.
// Pass 2: per (b,d,n) combine 16 chunk summaries -> per-chunk initial state.
// Pass 3: per (b,d,n,chunk) re-run local scan seeded with Hinit; y-reduce,
//         skip + gate epilogue, y overwrites delta in x-half of xz.
// Thread mapping (pass 1/3): n = g&15, d = (g>>4)&2047, b = (g>>15)&3,
// chunk = g>>17  (wave = 4 consecutive d for one b: keeps delta reads local).
// ---------------------------------------------------------------------------
__global__ __launch_bounds__(256) void scan_pass1(
    const float* __restrict__ xz, const float* __restrict__ u_,
    const float* __restrict__ x_dbl, const float* __restrict__ A_log,
    float* __restrict__ hfin, float* __restrict__ Pprod)
{
    const int g = blockIdx.x * 256 + threadIdx.x;  // 0 .. 2^21-1
    const int n = g & 15;
    const int d = (g >> 4) & (D_INNER - 1);
    const int b = (g >> 15) & 3;
    const int c = g >> 17;

    const float A = -__expf(A_log[d * D_STATE + n]);
    const int t0 = c * CHUNK;
    const size_t base4096 = (size_t)b * L_SEQ * 4096 + d;
    const size_t base2048 = (size_t)b * L_SEQ * D_INNER + d;
    const size_t base96   = (size_t)b * L_SEQ * 96;

    float h = 0.f, P = 1.f;
    #pragma unroll 4
    for (int i = 0; i < CHUNK; ++i) {
        const int t = t0 + i;
        const float dv = xz[base4096 + (size_t)t * 4096];
        const float uv = u_[base2048 + (size_t)t * D_INNER];
        const float Bv = x_dbl[base96 + (size_t)t * 96 + DT_RANK + n];
        const float a = __expf(dv * A);
        h = fmaf(h, a, dv * uv * Bv);
        P *= a;
    }
    const size_t idx = (((size_t)(b * D_INNER + d)) * NCHUNK + c) * D_STATE + n;
    hfin[idx]  = h;
    Pprod[idx] = P;
}

__global__ __launch_bounds__(256) void scan_pass2(
    const float* __restrict__ hfin, const float* __restrict__ Pprod,
    float* __restrict__ Hinit)
{
    const int g = blockIdx.x * 256 + threadIdx.x;  // 0 .. 131071
    const int n = g & 15;
    const int d = (g >> 4) & (D_INNER - 1);
    const int b = g >> 15;
    const size_t base = ((size_t)(b * D_INNER + d)) * NCHUNK * D_STATE + n;

    float H = 0.f;
    #pragma unroll
    for (int c = 0; c < NCHUNK; ++c) {
        Hinit[base + (size_t)c * D_STATE] = H;
        H = fmaf(H, Pprod[base + (size_t)c * D_STATE], hfin[base + (size_t)c * D_STATE]);
    }
}

__global__ __launch_bounds__(256) void scan_pass3(
    float* xz, const float* __restrict__ u_,
    const float* __restrict__ x_dbl, const float* __restrict__ A_log,
    const float* __restrict__ D_skip, const float* __restrict__ Hinit)
{
    const int g = blockIdx.x * 256 + threadIdx.x;
    const int n = g & 15;
    const int d = (g >> 4) & (D_INNER - 1);
    const int b = (g >> 15) & 3;
    const int c = g >> 17;

    const float A = -__expf(A_log[d * D_STATE + n]);
    const float Dd = D_skip[d];
    const int t0 = c * CHUNK;
    const size_t base4096 = (size_t)b * L_SEQ * 4096;
    const size_t base2048 = (size_t)b * L_SEQ * D_INNER + d;
    const size_t base96   = (size_t)b * L_SEQ * 96;

    float h = Hinit[(((size_t)(b * D_INNER + d)) * NCHUNK + c) * D_STATE + n];
    #pragma unroll 2
    for (int i = 0; i < CHUNK; ++i) {
        const int t = t0 + i;
        const float dv = xz[base4096 + (size_t)t * 4096 + d];           // delta
        const float uv = u_[base2048 + (size_t)t * D_INNER];
        const float Bv = x_dbl[base96 + (size_t)t * 96 + DT_RANK + n];
        const float Cv = x_dbl[base96 + (size_t)t * 96 + DT_RANK + D_STATE + n];

        const float a = __expf(dv * A);
        h = fmaf(h, a, dv * uv * Bv);
        float y = h * Cv;
        y += __shfl_xor(y, 1);
        y += __shfl_xor(y, 2);
        y += __shfl_xor(y, 4);
        y += __shfl_xor(y, 8);
        if (n == 0) {
            const float zv = xz[base4096 + (size_t)t * 4096 + D_INNER + d];
            const float sig = 1.f / (1.f + __expf(-zv));
            const float yv = (y + uv * Dd) * (zv * sig);
            xz[base4096 + (size_t)t * 4096 + d] = yv;                   // y over delta
        }
    }
}

// ---------------------------------------------------------------------------
extern "C" void kernel_launch(void* const* d_in, const int* in_sizes, int n_in,
                              void* d_out, int out_size, void* d_ws, size_t ws_size,
                              hipStream_t stream)
{
    const float* hs         = (const float*)d_in[0];
    const float* in_proj_w  = (const float*)d_in[1];
    const float* conv_w     = (const float*)d_in[2];
    const float* conv_b     = (const float*)d_in[3];
    const float* x_proj_w   = (const float*)d_in[4];
    const float* dt_proj_w  = (const float*)d_in[5];
    const float* dt_proj_b  = (const float*)d_in[6];
    const float* A_log      = (const float*)d_in[7];
    const float* D_skip     = (const float*)d_in[8];
    const float* out_proj_w = (const float*)d_in[9];
    float* out = (float*)d_out;

    // Workspace (fp32 elems):
    //   xz      NROW*4096 = 33,554,432  (134.2 MB)  x-half reused: delta, then y
    //   x_bld   NROW*2048 = 16,777,216  ( 67.1 MB)
    //   x_dbl   NROW*96   =    786,432  (  3.1 MB)
    //   hfin/Pprod/Hinit  3 * 2,097,152 ( 25.2 MB)
    // total ~229.6 MB
    float* ws    = (float*)d_ws;
    float* xz    = ws;
    float* x_bld = xz + (size_t)NROW * 4096;
    float* x_dbl = x_bld + (size_t)NROW * 2048;
    float* hfin  = x_dbl + (size_t)NROW * 96;
    float* Pprod = hfin + (size_t)B_SZ * D_INNER * NCHUNK * D_STATE;
    float* Hinit = Pprod + (size_t)B_SZ * D_INNER * NCHUNK * D_STATE;

    // K1: xz = hs @ in_proj_w        [8192,1024] @ [1024,4096]
    {
        dim3 grid(4096 / 64, NROW / 64);
        hipLaunchKernelGGL(gemm_f32, grid, dim3(256), 0, stream,
                           hs, in_proj_w, xz, NROW, 4096, D_MODEL, D_MODEL, 4096, 4096);
    }
    // K2: depthwise conv + bias + silu -> x_bld
    {
        const int total = B_SZ * L_SEQ * D_INNER;
        hipLaunchKernelGGL(conv_silu_kernel, dim3((total + 255) / 256), dim3(256), 0, stream,
                           xz, conv_w, conv_b, x_bld);
    }
    // K3: x_dbl = x_bld @ x_proj_w   [8192,2048] @ [2048,96]
    {
        dim3 grid((96 + 63) / 64, NROW / 64);
        hipLaunchKernelGGL(gemm_f32, grid, dim3(256), 0, stream,
                           x_bld, x_proj_w, x_dbl, NROW, 96, D_INNER, D_INNER, 96, 96);
    }
    // K4: delta -> x-half of xz
    {
        dim3 grid(D_INNER / 256, NROW / 16);
        hipLaunchKernelGGL(dt_softplus_kernel, grid, dim3(256), 0, stream,
                           x_dbl, dt_proj_w, dt_proj_b, xz);
    }
    // K5a/b/c: chunked scan
    {
        const int total1 = B_SZ * D_INNER * D_STATE * NCHUNK;  // 2,097,152
        hipLaunchKernelGGL(scan_pass1, dim3(total1 / 256), dim3(256), 0, stream,
                           xz, x_bld, x_dbl, A_log, hfin, Pprod);
        const int total2 = B_SZ * D_INNER * D_STATE;           // 131,072
        hipLaunchKernelGGL(scan_pass2, dim3(total2 / 256), dim3(256), 0, stream,
                           hfin, Pprod, Hinit);
        hipLaunchKernelGGL(scan_pass3, dim3(total1 / 256), dim3(256), 0, stream,
                           xz, x_bld, x_dbl, A_log, D_skip, Hinit);
    }
    // K6: out = y @ out_proj_w       [8192,2048(stride 4096)] @ [2048,1024]
    {
        dim3 grid(D_MODEL / 64, NROW / 64);
        hipLaunchKernelGGL(gemm_f32, grid, dim3(256), 0, stream,
                           xz, out_proj_w, out, NROW, D_MODEL, D_INNER, 4096, D_MODEL, D_MODEL);
    }
}

// Round 4
// 1195.336 us; speedup vs baseline: 2.9888x; 2.1260x over previous
//
#include <hip/hip_runtime.h>

#define B_SZ 4
#define L_SEQ 2048
#define D_MODEL 1024
#define D_INNER 2048
#define D_STATE 16
#define DT_RANK 64
#define NROW (B_SZ * L_SEQ)   // 8192
#define NCHUNK 16
#define CHUNK (L_SEQ / NCHUNK)  // 128

typedef __bf16 bf16x8 __attribute__((ext_vector_type(8)));
typedef float  f32x4  __attribute__((ext_vector_type(4)));

__device__ __forceinline__ ushort f2bf(float f) {
    union { float f; uint32_t u; } v; v.f = f;
    const uint32_t r = (v.u + 0x7FFFu + ((v.u >> 16) & 1u)) >> 16;  // RNE
    return (ushort)r;
}

// ---------------------------------------------------------------------------
// fp32 -> bf16 flat convert (4 elems/thread)
// ---------------------------------------------------------------------------
__global__ __launch_bounds__(256) void convert_bf16_flat(
    const float* __restrict__ in, ushort* __restrict__ out, int n4)
{
    const int i = blockIdx.x * 256 + threadIdx.x;
    if (i >= n4) return;
    const float4 v = reinterpret_cast<const float4*>(in)[i];
    ushort4 o; o.x = f2bf(v.x); o.y = f2bf(v.y); o.z = f2bf(v.z); o.w = f2bf(v.w);
    reinterpret_cast<ushort4*>(out)[i] = o;
}

// ---------------------------------------------------------------------------
// W[K,N] fp32 -> Wt[N,K] bf16 (32x32 LDS tile transpose)
// ---------------------------------------------------------------------------
__global__ __launch_bounds__(256) void transpose_bf16(
    const float* __restrict__ W, ushort* __restrict__ Wt, int K, int N)
{
    __shared__ float tile[32][33];
    const int n0 = blockIdx.x * 32, k0 = blockIdx.y * 32;
    const int c = threadIdx.x & 31, r = threadIdx.x >> 5;
    #pragma unroll
    for (int p = 0; p < 4; ++p)
        tile[r + p * 8][c] = W[(size_t)(k0 + r + p * 8) * N + n0 + c];
    __syncthreads();
    #pragma unroll
    for (int p = 0; p < 4; ++p)
        Wt[(size_t)(n0 + r + p * 8) * K + k0 + c] = f2bf(tile[c][r + p * 8]);
}

// ---------------------------------------------------------------------------
// y fp32 (x-half of xz, row stride 4096) -> y_bf [8192][2048] bf16
// ---------------------------------------------------------------------------
__global__ __launch_bounds__(256) void convert_y_bf16(
    const float* __restrict__ xz, ushort* __restrict__ ybf)
{
    const int i = blockIdx.x * 256 + threadIdx.x;  // group of 4 elems
    const int m = i >> 9;        // 512 groups of 4 per 2048-row
    const int d4 = (i & 511) * 4;
    const float4 v = *reinterpret_cast<const float4*>(&xz[(size_t)m * 4096 + d4]);
    ushort4 o; o.x = f2bf(v.x); o.y = f2bf(v.y); o.z = f2bf(v.z); o.w = f2bf(v.w);
    *reinterpret_cast<ushort4*>(&ybf[(size_t)m * 2048 + d4]) = o;
}

// ---------------------------------------------------------------------------
// bf16 NT GEMM: C[M,N](f32) = A[M,K](bf16) * Bt[N,K](bf16)^T
// 128x128 tile, BK=64, 256 thr = 4 waves (2x2), 4x4 16x16x32 MFMA frags/wave.
// LDS rows padded +8 bf16 (16B) -> ~2-way bank conflicts (free per m136).
// ---------------------------------------------------------------------------
__global__ __launch_bounds__(256) void gemm_bf16_nt(
    const ushort* __restrict__ A, const ushort* __restrict__ Bt,
    float* __restrict__ C, int M, int N, int K, int ldc)
{
    __shared__ ushort Alds[128][72];
    __shared__ ushort Blds[128][72];
    const int tid  = threadIdx.x;
    const int lane = tid & 63;
    const int wid  = tid >> 6;
    const int wr = wid >> 1, wc = wid & 1;
    const int m0 = blockIdx.y * 128, n0 = blockIdx.x * 128;
    const int l15 = lane & 15, l16 = lane >> 4;

    f32x4 acc[4][4] = {};

    const int sr = tid >> 1;           // staging row 0..127
    const int sk = (tid & 1) * 32;     // staging k-offset 0/32

    for (int k0 = 0; k0 < K; k0 += 64) {
        const uint4* ga = reinterpret_cast<const uint4*>(A  + (size_t)(m0 + sr) * K + k0 + sk);
        const uint4* gb = reinterpret_cast<const uint4*>(Bt + (size_t)(n0 + sr) * K + k0 + sk);
        const uint4 a0 = ga[0], a1 = ga[1], a2 = ga[2], a3 = ga[3];
        const uint4 b0 = gb[0], b1 = gb[1], b2 = gb[2], b3 = gb[3];
        *reinterpret_cast<uint4*>(&Alds[sr][sk])      = a0;
        *reinterpret_cast<uint4*>(&Alds[sr][sk + 8])  = a1;
        *reinterpret_cast<uint4*>(&Alds[sr][sk + 16]) = a2;
        *reinterpret_cast<uint4*>(&Alds[sr][sk + 24]) = a3;
        *reinterpret_cast<uint4*>(&Blds[sr][sk])      = b0;
        *reinterpret_cast<uint4*>(&Blds[sr][sk + 8])  = b1;
        *reinterpret_cast<uint4*>(&Blds[sr][sk + 16]) = b2;
        *reinterpret_cast<uint4*>(&Blds[sr][sk + 24]) = b3;
        __syncthreads();
        #pragma unroll
        for (int ks = 0; ks < 64; ks += 32) {
            bf16x8 af[4], bfr[4];
            #pragma unroll
            for (int mi = 0; mi < 4; ++mi)
                af[mi] = *reinterpret_cast<const bf16x8*>(&Alds[wr * 64 + mi * 16 + l15][ks + l16 * 8]);
            #pragma unroll
            for (int ni = 0; ni < 4; ++ni)
                bfr[ni] = *reinterpret_cast<const bf16x8*>(&Blds[wc * 64 + ni * 16 + l15][ks + l16 * 8]);
            #pragma unroll
            for (int mi = 0; mi < 4; ++mi)
                #pragma unroll
                for (int ni = 0; ni < 4; ++ni)
                    acc[mi][ni] = __builtin_amdgcn_mfma_f32_16x16x32_bf16(af[mi], bfr[ni], acc[mi][ni], 0, 0, 0);
        }
        __syncthreads();
    }

    #pragma unroll
    for (int mi = 0; mi < 4; ++mi) {
        const int mrow = m0 + wr * 64 + mi * 16 + l16 * 4;
        #pragma unroll
        for (int ni = 0; ni < 4; ++ni) {
            const int ncol = n0 + wc * 64 + ni * 16 + l15;
            #pragma unroll
            for (int r = 0; r < 4; ++r)
                C[(size_t)(mrow + r) * ldc + ncol] = acc[mi][ni][r];
        }
    }
}

// ---------------------------------------------------------------------------
// Generic tiled fp32 GEMM (kept for K3: N=96).
// ---------------------------------------------------------------------------
__global__ __launch_bounds__(256) void gemm_f32(
    const float* __restrict__ A, const float* __restrict__ B, float* __restrict__ C,
    int M, int N, int K, int lda, int ldb, int ldc)
{
    __shared__ __align__(16) float As[16][68];
    __shared__ __align__(16) float Bs[16][68];
    const int tid = threadIdx.x;
    const int tx = tid & 15, ty = tid >> 4;
    const int m0 = blockIdx.y * 64, n0 = blockIdx.x * 64;

    float c[4][4] = {};

    for (int k0 = 0; k0 < K; k0 += 16) {
        {
            const int ka = tid & 15, ma = tid >> 4;
            #pragma unroll
            for (int p = 0; p < 4; ++p) {
                const int m = ma + p * 16;
                float v = 0.f;
                if (m0 + m < M && k0 + ka < K) v = A[(size_t)(m0 + m) * lda + k0 + ka];
                As[ka][m] = v;
            }
        }
        {
            const int nb = tid & 63, kb = tid >> 6;
            #pragma unroll
            for (int p = 0; p < 4; ++p) {
                const int k = kb + p * 4;
                float v = 0.f;
                if (k0 + k < K && n0 + nb < N) v = B[(size_t)(k0 + k) * ldb + n0 + nb];
                Bs[k][nb] = v;
            }
        }
        __syncthreads();
        #pragma unroll
        for (int kk = 0; kk < 16; ++kk) {
            const float4 av = *reinterpret_cast<const float4*>(&As[kk][ty * 4]);
            const float4 bv = *reinterpret_cast<const float4*>(&Bs[kk][tx * 4]);
            const float a[4] = {av.x, av.y, av.z, av.w};
            const float b[4] = {bv.x, bv.y, bv.z, bv.w};
            #pragma unroll
            for (int i = 0; i < 4; ++i)
                #pragma unroll
                for (int j = 0; j < 4; ++j)
                    c[i][j] = fmaf(a[i], b[j], c[i][j]);
        }
        __syncthreads();
    }

    #pragma unroll
    for (int i = 0; i < 4; ++i) {
        const int m = m0 + ty * 4 + i;
        if (m >= M) continue;
        #pragma unroll
        for (int j = 0; j < 4; ++j) {
            const int n = n0 + tx * 4 + j;
            if (n < N) C[(size_t)m * ldc + n] = c[i][j];
        }
    }
}

// ---------------------------------------------------------------------------
// Depthwise conv (taps x[t-6..t-3]) + bias + SiLU.
// ---------------------------------------------------------------------------
__global__ __launch_bounds__(256) void conv_silu_kernel(
    const float* __restrict__ xz, const float* __restrict__ conv_w,
    const float* __restrict__ conv_b, float* __restrict__ x_bld)
{
    const int idx = blockIdx.x * 256 + threadIdx.x;
    if (idx >= B_SZ * L_SEQ * D_INNER) return;
    const int d = idx & (D_INNER - 1);
    const int t = (idx >> 11) & (L_SEQ - 1);
    const int b = idx >> 22;

    const float4 w = *reinterpret_cast<const float4*>(&conv_w[d * 4]);
    const float wk[4] = {w.x, w.y, w.z, w.w};
    float acc = conv_b[d];
    const size_t rowbase = (size_t)b * L_SEQ * 4096 + d;
    #pragma unroll
    for (int k = 0; k < 4; ++k) {
        const int tt = t - 6 + k;
        if (tt >= 0) acc = fmaf(wk[k], xz[rowbase + (size_t)tt * 4096], acc);
    }
    const float s = acc / (1.f + __expf(-acc));
    x_bld[idx] = s;
}

// ---------------------------------------------------------------------------
// delta = softplus(dt_low @ dt_proj_w + 2*bias) -> x-half of xz (stride 4096)
// ---------------------------------------------------------------------------
__global__ __launch_bounds__(256) void dt_softplus_kernel(
    const float* __restrict__ x_dbl, const float* __restrict__ W,
    const float* __restrict__ bias, float* __restrict__ delta_xz)
{
    __shared__ float a[16][64];
    const int tid = threadIdx.x;
    const int m0 = blockIdx.y * 16;
    const int d = blockIdx.x * 256 + tid;

    {
        const int r = tid & 63, i = tid >> 6;
        #pragma unroll
        for (int p = 0; p < 4; ++p)
            a[i + p * 4][r] = x_dbl[(size_t)(m0 + i + p * 4) * 96 + r];
    }
    __syncthreads();

    float acc[16] = {};
    for (int r = 0; r < 64; ++r) {
        const float w = W[(size_t)r * D_INNER + d];
        #pragma unroll
        for (int mi = 0; mi < 16; ++mi) acc[mi] = fmaf(a[mi][r], w, acc[mi]);
    }
    const float b2 = 2.0f * bias[d];
    #pragma unroll
    for (int mi = 0; mi < 16; ++mi) {
        const float v = acc[mi] + b2;
        const float sp = (v > 20.0f) ? v : log1pf(__expf(v));
        delta_xz[(size_t)(m0 + mi) * 4096 + d] = sp;
    }
}

// ---------------------------------------------------------------------------
// Chunked parallel scan (3 passes, affine recurrence h = a*h + b).
// ---------------------------------------------------------------------------
__global__ __launch_bounds__(256) void scan_pass1(
    const float* __restrict__ xz, const float* __restrict__ u_,
    const float* __restrict__ x_dbl, const float* __restrict__ A_log,
    float* __restrict__ hfin, float* __restrict__ Pprod)
{
    const int g = blockIdx.x * 256 + threadIdx.x;
    const int n = g & 15;
    const int d = (g >> 4) & (D_INNER - 1);
    const int b = (g >> 15) & 3;
    const int c = g >> 17;

    const float A = -__expf(A_log[d * D_STATE + n]);
    const int t0 = c * CHUNK;
    const size_t base4096 = (size_t)b * L_SEQ * 4096 + d;
    const size_t base2048 = (size_t)b * L_SEQ * D_INNER + d;
    const size_t base96   = (size_t)b * L_SEQ * 96;

    float h = 0.f, P = 1.f;
    #pragma unroll 4
    for (int i = 0; i < CHUNK; ++i) {
        const int t = t0 + i;
        const float dv = xz[base4096 + (size_t)t * 4096];
        const float uv = u_[base2048 + (size_t)t * D_INNER];
        const float Bv = x_dbl[base96 + (size_t)t * 96 + DT_RANK + n];
        const float a = __expf(dv * A);
        h = fmaf(h, a, dv * uv * Bv);
        P *= a;
    }
    const size_t idx = (((size_t)(b * D_INNER + d)) * NCHUNK + c) * D_STATE + n;
    hfin[idx]  = h;
    Pprod[idx] = P;
}

__global__ __launch_bounds__(256) void scan_pass2(
    const float* __restrict__ hfin, const float* __restrict__ Pprod,
    float* __restrict__ Hinit)
{
    const int g = blockIdx.x * 256 + threadIdx.x;
    const int n = g & 15;
    const int d = (g >> 4) & (D_INNER - 1);
    const int b = g >> 15;
    const size_t base = ((size_t)(b * D_INNER + d)) * NCHUNK * D_STATE + n;

    float H = 0.f;
    #pragma unroll
    for (int c = 0; c < NCHUNK; ++c) {
        Hinit[base + (size_t)c * D_STATE] = H;
        H = fmaf(H, Pprod[base + (size_t)c * D_STATE], hfin[base + (size_t)c * D_STATE]);
    }
}

__global__ __launch_bounds__(256) void scan_pass3(
    float* xz, const float* __restrict__ u_,
    const float* __restrict__ x_dbl, const float* __restrict__ A_log,
    const float* __restrict__ D_skip, const float* __restrict__ Hinit)
{
    const int g = blockIdx.x * 256 + threadIdx.x;
    const int n = g & 15;
    const int d = (g >> 4) & (D_INNER - 1);
    const int b = (g >> 15) & 3;
    const int c = g >> 17;

    const float A = -__expf(A_log[d * D_STATE + n]);
    const float Dd = D_skip[d];
    const int t0 = c * CHUNK;
    const size_t base4096 = (size_t)b * L_SEQ * 4096;
    const size_t base2048 = (size_t)b * L_SEQ * D_INNER + d;
    const size_t base96   = (size_t)b * L_SEQ * 96;

    float h = Hinit[(((size_t)(b * D_INNER + d)) * NCHUNK + c) * D_STATE + n];
    #pragma unroll 2
    for (int i = 0; i < CHUNK; ++i) {
        const int t = t0 + i;
        const float dv = xz[base4096 + (size_t)t * 4096 + d];           // delta
        const float uv = u_[base2048 + (size_t)t * D_INNER];
        const float Bv = x_dbl[base96 + (size_t)t * 96 + DT_RANK + n];
        const float Cv = x_dbl[base96 + (size_t)t * 96 + DT_RANK + D_STATE + n];

        const float a = __expf(dv * A);
        h = fmaf(h, a, dv * uv * Bv);
        float y = h * Cv;
        y += __shfl_xor(y, 1);
        y += __shfl_xor(y, 2);
        y += __shfl_xor(y, 4);
        y += __shfl_xor(y, 8);
        if (n == 0) {
            const float zv = xz[base4096 + (size_t)t * 4096 + D_INNER + d];
            const float sig = 1.f / (1.f + __expf(-zv));
            const float yv = (y + uv * Dd) * (zv * sig);
            xz[base4096 + (size_t)t * 4096 + d] = yv;                   // y over delta
        }
    }
}

// ---------------------------------------------------------------------------
extern "C" void kernel_launch(void* const* d_in, const int* in_sizes, int n_in,
                              void* d_out, int out_size, void* d_ws, size_t ws_size,
                              hipStream_t stream)
{
    const float* hs         = (const float*)d_in[0];
    const float* in_proj_w  = (const float*)d_in[1];
    const float* conv_w     = (const float*)d_in[2];
    const float* conv_b     = (const float*)d_in[3];
    const float* x_proj_w   = (const float*)d_in[4];
    const float* dt_proj_w  = (const float*)d_in[5];
    const float* dt_proj_b  = (const float*)d_in[6];
    const float* A_log      = (const float*)d_in[7];
    const float* D_skip     = (const float*)d_in[8];
    const float* out_proj_w = (const float*)d_in[9];
    float* out = (float*)d_out;

    // Workspace (f32 elem offsets), total 60,555,264 f32 = 242.2 MB:
    //   xz     134.2 MB   x-half reused: x -> delta -> y
    //   x_bld   67.1 MB
    //   x_dbl    3.1 MB
    //   R1      33.5 MB   phase A: hs_bf+Wt1 | phase B: hfin/Pprod/Hinit | phase C: y_bf
    //   wt6      4.2 MB
    float* ws    = (float*)d_ws;
    float* xz    = ws;
    float* x_bld = xz + (size_t)NROW * 4096;
    float* x_dbl = x_bld + (size_t)NROW * 2048;
    float* R1    = x_dbl + (size_t)NROW * 96;
    float* wt6f  = R1 + 8388608;

    ushort* hs_bf = (ushort*)R1;                       // 8,388,608 bf16
    ushort* Wt1   = (ushort*)(R1 + 4194304);           // 4,194,304 bf16 [4096,1024]
    float*  hfin  = R1;                                // 2,097,152 f32
    float*  Pprod = R1 + 2097152;
    float*  Hinit = R1 + 4194304;
    ushort* y_bf  = (ushort*)R1;                       // 16,777,216 bf16 [8192,2048]
    ushort* Wt6   = (ushort*)wt6f;                     // 2,097,152 bf16 [1024,2048]

    // C0: converts (hs flat; weights transposed to [N,K] bf16)
    hipLaunchKernelGGL(convert_bf16_flat, dim3(8192), dim3(256), 0, stream,
                       hs, hs_bf, NROW * D_MODEL / 4);
    hipLaunchKernelGGL(transpose_bf16, dim3(4096 / 32, 1024 / 32), dim3(256), 0, stream,
                       in_proj_w, Wt1, 1024, 4096);
    hipLaunchKernelGGL(transpose_bf16, dim3(1024 / 32, 2048 / 32), dim3(256), 0, stream,
                       out_proj_w, Wt6, 2048, 1024);

    // K1: xz = hs @ in_proj_w   (bf16 MFMA NT)  [8192,1024]x[4096,1024]^T
    hipLaunchKernelGGL(gemm_bf16_nt, dim3(4096 / 128, NROW / 128), dim3(256), 0, stream,
                       hs_bf, Wt1, xz, NROW, 4096, D_MODEL, 4096);

    // K2: depthwise conv + bias + silu -> x_bld
    {
        const int total = B_SZ * L_SEQ * D_INNER;
        hipLaunchKernelGGL(conv_silu_kernel, dim3((total + 255) / 256), dim3(256), 0, stream,
                           xz, conv_w, conv_b, x_bld);
    }
    // K3: x_dbl = x_bld @ x_proj_w   [8192,2048] @ [2048,96]  (fp32)
    {
        dim3 grid((96 + 63) / 64, NROW / 64);
        hipLaunchKernelGGL(gemm_f32, grid, dim3(256), 0, stream,
                           x_bld, x_proj_w, x_dbl, NROW, 96, D_INNER, D_INNER, 96, 96);
    }
    // K4: delta -> x-half of xz
    {
        dim3 grid(D_INNER / 256, NROW / 16);
        hipLaunchKernelGGL(dt_softplus_kernel, grid, dim3(256), 0, stream,
                           x_dbl, dt_proj_w, dt_proj_b, xz);
    }
    // K5: chunked scan
    {
        const int total1 = B_SZ * D_INNER * D_STATE * NCHUNK;
        hipLaunchKernelGGL(scan_pass1, dim3(total1 / 256), dim3(256), 0, stream,
                           xz, x_bld, x_dbl, A_log, hfin, Pprod);
        const int total2 = B_SZ * D_INNER * D_STATE;
        hipLaunchKernelGGL(scan_pass2, dim3(total2 / 256), dim3(256), 0, stream,
                           hfin, Pprod, Hinit);
        hipLaunchKernelGGL(scan_pass3, dim3(total1 / 256), dim3(256), 0, stream,
                           xz, x_bld, x_dbl, A_log, D_skip, Hinit);
    }
    // C1: y (x-half of xz) -> y_bf
    hipLaunchKernelGGL(convert_y_bf16, dim3(16384), dim3(256), 0, stream, xz, y_bf);

    // K6: out = y @ out_proj_w   (bf16 MFMA NT)  [8192,2048]x[1024,2048]^T
    hipLaunchKernelGGL(gemm_bf16_nt, dim3(1024 / 128, NROW / 128), dim3(256), 0, stream,
                       y_bf, Wt6, out, NROW, 1024, D_INNER, 1024);
}

// Round 5
// 826.722 us; speedup vs baseline: 4.3215x; 1.4459x over previous
//
#include <hip/hip_runtime.h>

#define B_SZ 4
#define L_SEQ 2048
#define D_MODEL 1024
#define D_INNER 2048
#define D_STATE 16
#define DT_RANK 64
#define NROW (B_SZ * L_SEQ)   // 8192
#define NCHUNK 64
#define CHUNK (L_SEQ / NCHUNK)  // 32

typedef __bf16 bf16x8 __attribute__((ext_vector_type(8)));
typedef float  f32x4  __attribute__((ext_vector_type(4)));

__device__ __forceinline__ ushort f2bf(float f) {
    union { float f; uint32_t u; } v; v.f = f;
    const uint32_t r = (v.u + 0x7FFFu + ((v.u >> 16) & 1u)) >> 16;  // RNE
    return (ushort)r;
}

// ---------------------------------------------------------------------------
// fp32 -> bf16 flat convert (4 elems/thread)
// ---------------------------------------------------------------------------
__global__ __launch_bounds__(256) void convert_bf16_flat(
    const float* __restrict__ in, ushort* __restrict__ out, int n4)
{
    const int i = blockIdx.x * 256 + threadIdx.x;
    if (i >= n4) return;
    const float4 v = reinterpret_cast<const float4*>(in)[i];
    ushort4 o; o.x = f2bf(v.x); o.y = f2bf(v.y); o.z = f2bf(v.z); o.w = f2bf(v.w);
    reinterpret_cast<ushort4*>(out)[i] = o;
}

// ---------------------------------------------------------------------------
// W[K,N] fp32 -> Wt[N,K] bf16 (32x32 LDS tile transpose)
// ---------------------------------------------------------------------------
__global__ __launch_bounds__(256) void transpose_bf16(
    const float* __restrict__ W, ushort* __restrict__ Wt, int K, int N)
{
    __shared__ float tile[32][33];
    const int n0 = blockIdx.x * 32, k0 = blockIdx.y * 32;
    const int c = threadIdx.x & 31, r = threadIdx.x >> 5;
    #pragma unroll
    for (int p = 0; p < 4; ++p)
        tile[r + p * 8][c] = W[(size_t)(k0 + r + p * 8) * N + n0 + c];
    __syncthreads();
    #pragma unroll
    for (int p = 0; p < 4; ++p)
        Wt[(size_t)(n0 + r + p * 8) * K + k0 + c] = f2bf(tile[c][r + p * 8]);
}

// ---------------------------------------------------------------------------
// y fp32 (x-half of xz, row stride 4096) -> y_bf [8192][2048] bf16
// ---------------------------------------------------------------------------
__global__ __launch_bounds__(256) void convert_y_bf16(
    const float* __restrict__ xz, ushort* __restrict__ ybf)
{
    const int i = blockIdx.x * 256 + threadIdx.x;
    const int m = i >> 9;
    const int d4 = (i & 511) * 4;
    const float4 v = *reinterpret_cast<const float4*>(&xz[(size_t)m * 4096 + d4]);
    ushort4 o; o.x = f2bf(v.x); o.y = f2bf(v.y); o.z = f2bf(v.z); o.w = f2bf(v.w);
    *reinterpret_cast<ushort4*>(&ybf[(size_t)m * 2048 + d4]) = o;
}

// ---------------------------------------------------------------------------
// bf16 NT GEMM: C[M,N](f32) = A[M,K](bf16) * Bt[N,K](bf16)^T
// ---------------------------------------------------------------------------
__global__ __launch_bounds__(256) void gemm_bf16_nt(
    const ushort* __restrict__ A, const ushort* __restrict__ Bt,
    float* __restrict__ C, int M, int N, int K, int ldc)
{
    __shared__ ushort Alds[128][72];
    __shared__ ushort Blds[128][72];
    const int tid  = threadIdx.x;
    const int lane = tid & 63;
    const int wid  = tid >> 6;
    const int wr = wid >> 1, wc = wid & 1;
    const int m0 = blockIdx.y * 128, n0 = blockIdx.x * 128;
    const int l15 = lane & 15, l16 = lane >> 4;

    f32x4 acc[4][4] = {};

    const int sr = tid >> 1;
    const int sk = (tid & 1) * 32;

    for (int k0 = 0; k0 < K; k0 += 64) {
        const uint4* ga = reinterpret_cast<const uint4*>(A  + (size_t)(m0 + sr) * K + k0 + sk);
        const uint4* gb = reinterpret_cast<const uint4*>(Bt + (size_t)(n0 + sr) * K + k0 + sk);
        const uint4 a0 = ga[0], a1 = ga[1], a2 = ga[2], a3 = ga[3];
        const uint4 b0 = gb[0], b1 = gb[1], b2 = gb[2], b3 = gb[3];
        *reinterpret_cast<uint4*>(&Alds[sr][sk])      = a0;
        *reinterpret_cast<uint4*>(&Alds[sr][sk + 8])  = a1;
        *reinterpret_cast<uint4*>(&Alds[sr][sk + 16]) = a2;
        *reinterpret_cast<uint4*>(&Alds[sr][sk + 24]) = a3;
        *reinterpret_cast<uint4*>(&Blds[sr][sk])      = b0;
        *reinterpret_cast<uint4*>(&Blds[sr][sk + 8])  = b1;
        *reinterpret_cast<uint4*>(&Blds[sr][sk + 16]) = b2;
        *reinterpret_cast<uint4*>(&Blds[sr][sk + 24]) = b3;
        __syncthreads();
        #pragma unroll
        for (int ks = 0; ks < 64; ks += 32) {
            bf16x8 af[4], bfr[4];
            #pragma unroll
            for (int mi = 0; mi < 4; ++mi)
                af[mi] = *reinterpret_cast<const bf16x8*>(&Alds[wr * 64 + mi * 16 + l15][ks + l16 * 8]);
            #pragma unroll
            for (int ni = 0; ni < 4; ++ni)
                bfr[ni] = *reinterpret_cast<const bf16x8*>(&Blds[wc * 64 + ni * 16 + l15][ks + l16 * 8]);
            #pragma unroll
            for (int mi = 0; mi < 4; ++mi)
                #pragma unroll
                for (int ni = 0; ni < 4; ++ni)
                    acc[mi][ni] = __builtin_amdgcn_mfma_f32_16x16x32_bf16(af[mi], bfr[ni], acc[mi][ni], 0, 0, 0);
        }
        __syncthreads();
    }

    #pragma unroll
    for (int mi = 0; mi < 4; ++mi) {
        const int mrow = m0 + wr * 64 + mi * 16 + l16 * 4;
        #pragma unroll
        for (int ni = 0; ni < 4; ++ni) {
            const int ncol = n0 + wc * 64 + ni * 16 + l15;
            #pragma unroll
            for (int r = 0; r < 4; ++r)
                C[(size_t)(mrow + r) * ldc + ncol] = acc[mi][ni][r];
        }
    }
}

// ---------------------------------------------------------------------------
// Generic tiled fp32 GEMM (kept for K3: N=96).
// ---------------------------------------------------------------------------
__global__ __launch_bounds__(256) void gemm_f32(
    const float* __restrict__ A, const float* __restrict__ B, float* __restrict__ C,
    int M, int N, int K, int lda, int ldb, int ldc)
{
    __shared__ __align__(16) float As[16][68];
    __shared__ __align__(16) float Bs[16][68];
    const int tid = threadIdx.x;
    const int tx = tid & 15, ty = tid >> 4;
    const int m0 = blockIdx.y * 64, n0 = blockIdx.x * 64;

    float c[4][4] = {};

    for (int k0 = 0; k0 < K; k0 += 16) {
        {
            const int ka = tid & 15, ma = tid >> 4;
            #pragma unroll
            for (int p = 0; p < 4; ++p) {
                const int m = ma + p * 16;
                float v = 0.f;
                if (m0 + m < M && k0 + ka < K) v = A[(size_t)(m0 + m) * lda + k0 + ka];
                As[ka][m] = v;
            }
        }
        {
            const int nb = tid & 63, kb = tid >> 6;
            #pragma unroll
            for (int p = 0; p < 4; ++p) {
                const int k = kb + p * 4;
                float v = 0.f;
                if (k0 + k < K && n0 + nb < N) v = B[(size_t)(k0 + k) * ldb + n0 + nb];
                Bs[k][nb] = v;
            }
        }
        __syncthreads();
        #pragma unroll
        for (int kk = 0; kk < 16; ++kk) {
            const float4 av = *reinterpret_cast<const float4*>(&As[kk][ty * 4]);
            const float4 bv = *reinterpret_cast<const float4*>(&Bs[kk][tx * 4]);
            const float a[4] = {av.x, av.y, av.z, av.w};
            const float b[4] = {bv.x, bv.y, bv.z, bv.w};
            #pragma unroll
            for (int i = 0; i < 4; ++i)
                #pragma unroll
                for (int j = 0; j < 4; ++j)
                    c[i][j] = fmaf(a[i], b[j], c[i][j]);
        }
        __syncthreads();
    }

    #pragma unroll
    for (int i = 0; i < 4; ++i) {
        const int m = m0 + ty * 4 + i;
        if (m >= M) continue;
        #pragma unroll
        for (int j = 0; j < 4; ++j) {
            const int n = n0 + tx * 4 + j;
            if (n < N) C[(size_t)m * ldc + n] = c[i][j];
        }
    }
}

// ---------------------------------------------------------------------------
// Depthwise conv (taps x[t-6..t-3]) + bias + SiLU.
// ---------------------------------------------------------------------------
__global__ __launch_bounds__(256) void conv_silu_kernel(
    const float* __restrict__ xz, const float* __restrict__ conv_w,
    const float* __restrict__ conv_b, float* __restrict__ x_bld)
{
    const int idx = blockIdx.x * 256 + threadIdx.x;
    if (idx >= B_SZ * L_SEQ * D_INNER) return;
    const int d = idx & (D_INNER - 1);
    const int t = (idx >> 11) & (L_SEQ - 1);
    const int b = idx >> 22;

    const float4 w = *reinterpret_cast<const float4*>(&conv_w[d * 4]);
    const float wk[4] = {w.x, w.y, w.z, w.w};
    float acc = conv_b[d];
    const size_t rowbase = (size_t)b * L_SEQ * 4096 + d;
    #pragma unroll
    for (int k = 0; k < 4; ++k) {
        const int tt = t - 6 + k;
        if (tt >= 0) acc = fmaf(wk[k], xz[rowbase + (size_t)tt * 4096], acc);
    }
    const float s = acc / (1.f + __expf(-acc));
    x_bld[idx] = s;
}

// ---------------------------------------------------------------------------
// delta = softplus(dt_low @ dt_proj_w + 2*bias) -> x-half of xz (stride 4096)
// ---------------------------------------------------------------------------
__global__ __launch_bounds__(256) void dt_softplus_kernel(
    const float* __restrict__ x_dbl, const float* __restrict__ W,
    const float* __restrict__ bias, float* __restrict__ delta_xz)
{
    __shared__ float a[16][64];
    const int tid = threadIdx.x;
    const int m0 = blockIdx.y * 16;
    const int d = blockIdx.x * 256 + tid;

    {
        const int r = tid & 63, i = tid >> 6;
        #pragma unroll
        for (int p = 0; p < 4; ++p)
            a[i + p * 4][r] = x_dbl[(size_t)(m0 + i + p * 4) * 96 + r];
    }
    __syncthreads();

    float acc[16] = {};
    for (int r = 0; r < 64; ++r) {
        const float w = W[(size_t)r * D_INNER + d];
        #pragma unroll
        for (int mi = 0; mi < 16; ++mi) acc[mi] = fmaf(a[mi][r], w, acc[mi]);
    }
    const float b2 = 2.0f * bias[d];
    #pragma unroll
    for (int mi = 0; mi < 16; ++mi) {
        const float v = acc[mi] + b2;
        const float sp = (v > 20.0f) ? v : log1pf(__expf(v));
        delta_xz[(size_t)(m0 + mi) * 4096 + d] = sp;
    }
}

// ---------------------------------------------------------------------------
// Chunked parallel scan, thread-local 16-state version.
// Thread = (b, d, chunk): d = g&2047, b = (g>>11)&3, c = g>>13.
// h[16] lives in VGPRs; 16 independent recurrence chains give ILP; the
// n-reduction is 16 in-thread FMAs (no cross-lane ops); dv/uv loaded once.
// Cumprod collapses analytically: P[n] = exp(A[n] * sum_t dv) -> pass1 stores
// only h[16] + 1 scalar Ssum. Pass2 rebuilds P on the fly and converts
// hfin -> Hinit IN PLACE.
// ---------------------------------------------------------------------------
__global__ __launch_bounds__(256) void scan_pass1(
    const float* __restrict__ xz, const float* __restrict__ u_,
    const float* __restrict__ x_dbl, const float* __restrict__ A_log,
    float* __restrict__ hfin, float* __restrict__ Ssum)
{
    const int g = blockIdx.x * 256 + threadIdx.x;  // 0 .. 524287
    const int d = g & (D_INNER - 1);
    const int b = (g >> 11) & 3;
    const int c = g >> 13;

    float A[D_STATE];
    #pragma unroll
    for (int q = 0; q < 4; ++q) {
        const float4 al = *reinterpret_cast<const float4*>(&A_log[d * D_STATE + q * 4]);
        A[q * 4 + 0] = -__expf(al.x); A[q * 4 + 1] = -__expf(al.y);
        A[q * 4 + 2] = -__expf(al.z); A[q * 4 + 3] = -__expf(al.w);
    }

    const int t0 = c * CHUNK;
    const size_t base4096 = (size_t)b * L_SEQ * 4096 + d;
    const size_t base2048 = (size_t)b * L_SEQ * D_INNER + d;
    const size_t base96   = (size_t)b * L_SEQ * 96;

    float h[D_STATE] = {};
    float S = 0.f;
    for (int i = 0; i < CHUNK; ++i) {
        const int t = t0 + i;
        const float dv = xz[base4096 + (size_t)t * 4096];   // delta
        const float uv = u_[base2048 + (size_t)t * D_INNER];
        float Bv[D_STATE];
        #pragma unroll
        for (int q = 0; q < 4; ++q)
            *reinterpret_cast<float4*>(&Bv[q * 4]) =
                *reinterpret_cast<const float4*>(&x_dbl[base96 + (size_t)t * 96 + DT_RANK + q * 4]);
        const float du = dv * uv;
        S += dv;
        #pragma unroll
        for (int n = 0; n < D_STATE; ++n)
            h[n] = fmaf(h[n], __expf(dv * A[n]), du * Bv[n]);
    }
    const size_t sidx = (size_t)(c * B_SZ + b) * D_INNER + d;
    #pragma unroll
    for (int q = 0; q < 4; ++q)
        *reinterpret_cast<float4*>(&hfin[sidx * D_STATE + q * 4]) =
            *reinterpret_cast<const float4*>(&h[q * 4]);
    Ssum[sidx] = S;
}

__global__ __launch_bounds__(256) void scan_pass2(
    float* __restrict__ hfin, const float* __restrict__ Ssum,
    const float* __restrict__ A_log)
{
    const int g = blockIdx.x * 256 + threadIdx.x;  // 0 .. 131071
    const int n = g & 15;
    const int d = (g >> 4) & (D_INNER - 1);
    const int b = g >> 15;
    const float A = -__expf(A_log[d * D_STATE + n]);

    float H = 0.f;
    #pragma unroll 4
    for (int c = 0; c < NCHUNK; ++c) {
        const size_t sidx = (size_t)(c * B_SZ + b) * D_INNER + d;
        const float P = __expf(A * Ssum[sidx]);
        const float hc = hfin[sidx * D_STATE + n];
        hfin[sidx * D_STATE + n] = H;       // Hinit in place
        H = fmaf(H, P, hc);
    }
}

__global__ __launch_bounds__(256) void scan_pass3(
    float* xz, const float* __restrict__ u_,
    const float* __restrict__ x_dbl, const float* __restrict__ A_log,
    const float* __restrict__ D_skip, const float* __restrict__ Hinit)
{
    const int g = blockIdx.x * 256 + threadIdx.x;  // 0 .. 524287
    const int d = g & (D_INNER - 1);
    const int b = (g >> 11) & 3;
    const int c = g >> 13;

    float A[D_STATE];
    #pragma unroll
    for (int q = 0; q < 4; ++q) {
        const float4 al = *reinterpret_cast<const float4*>(&A_log[d * D_STATE + q * 4]);
        A[q * 4 + 0] = -__expf(al.x); A[q * 4 + 1] = -__expf(al.y);
        A[q * 4 + 2] = -__expf(al.z); A[q * 4 + 3] = -__expf(al.w);
    }
    const float Dd = D_skip[d];

    const int t0 = c * CHUNK;
    const size_t base4096 = (size_t)b * L_SEQ * 4096;
    const size_t base2048 = (size_t)b * L_SEQ * D_INNER + d;
    const size_t base96   = (size_t)b * L_SEQ * 96;

    float h[D_STATE];
    const size_t sidx = (size_t)(c * B_SZ + b) * D_INNER + d;
    #pragma unroll
    for (int q = 0; q < 4; ++q)
        *reinterpret_cast<float4*>(&h[q * 4]) =
            *reinterpret_cast<const float4*>(&Hinit[sidx * D_STATE + q * 4]);

    for (int i = 0; i < CHUNK; ++i) {
        const int t = t0 + i;
        const float dv = xz[base4096 + (size_t)t * 4096 + d];           // delta
        const float uv = u_[base2048 + (size_t)t * D_INNER];
        const float zv = xz[base4096 + (size_t)t * 4096 + D_INNER + d];
        float Bv[D_STATE], Cv[D_STATE];
        #pragma unroll
        for (int q = 0; q < 4; ++q) {
            *reinterpret_cast<float4*>(&Bv[q * 4]) =
                *reinterpret_cast<const float4*>(&x_dbl[base96 + (size_t)t * 96 + DT_RANK + q * 4]);
            *reinterpret_cast<float4*>(&Cv[q * 4]) =
                *reinterpret_cast<const float4*>(&x_dbl[base96 + (size_t)t * 96 + DT_RANK + D_STATE + q * 4]);
        }
        const float du = dv * uv;
        float y = 0.f;
        #pragma unroll
        for (int n = 0; n < D_STATE; ++n) {
            h[n] = fmaf(h[n], __expf(dv * A[n]), du * Bv[n]);
            y = fmaf(h[n], Cv[n], y);
        }
        const float sig = 1.f / (1.f + __expf(-zv));
        const float yv = (y + uv * Dd) * (zv * sig);
        xz[base4096 + (size_t)t * 4096 + d] = yv;                       // y over delta
    }
}

// ---------------------------------------------------------------------------
extern "C" void kernel_launch(void* const* d_in, const int* in_sizes, int n_in,
                              void* d_out, int out_size, void* d_ws, size_t ws_size,
                              hipStream_t stream)
{
    const float* hs         = (const float*)d_in[0];
    const float* in_proj_w  = (const float*)d_in[1];
    const float* conv_w     = (const float*)d_in[2];
    const float* conv_b     = (const float*)d_in[3];
    const float* x_proj_w   = (const float*)d_in[4];
    const float* dt_proj_w  = (const float*)d_in[5];
    const float* dt_proj_b  = (const float*)d_in[6];
    const float* A_log      = (const float*)d_in[7];
    const float* D_skip     = (const float*)d_in[8];
    const float* out_proj_w = (const float*)d_in[9];
    float* out = (float*)d_out;

    // Workspace (f32 elems), total 61,079,552 f32 = 244.3 MB:
    //   xz     134.2 MB  x-half reused: x -> delta -> y
    //   x_bld   67.1 MB
    //   x_dbl    3.1 MB
    //   R1      35.7 MB  phase A: hs_bf+Wt1 (25.2) | phase B: hfin 33.5 + Ssum 2.1
    //                    | phase C: y_bf 33.5
    //   Wt6      4.2 MB
    float* ws    = (float*)d_ws;
    float* xz    = ws;
    float* x_bld = xz + (size_t)NROW * 4096;
    float* x_dbl = x_bld + (size_t)NROW * 2048;
    float* R1    = x_dbl + (size_t)NROW * 96;
    float* wt6f  = R1 + 8912896;

    ushort* hs_bf = (ushort*)R1;                       // 8,388,608 bf16
    ushort* Wt1   = (ushort*)(R1 + 4194304);           // 4,194,304 bf16 [4096,1024]
    float*  hfin  = R1;                                // 8,388,608 f32
    float*  Ssum  = R1 + 8388608;                      //   524,288 f32
    ushort* y_bf  = (ushort*)R1;                       // 16,777,216 bf16 [8192,2048]
    ushort* Wt6   = (ushort*)wt6f;                     // 2,097,152 bf16 [1024,2048]

    // C0: converts (hs flat; weights transposed to [N,K] bf16)
    hipLaunchKernelGGL(convert_bf16_flat, dim3(8192), dim3(256), 0, stream,
                       hs, hs_bf, NROW * D_MODEL / 4);
    hipLaunchKernelGGL(transpose_bf16, dim3(4096 / 32, 1024 / 32), dim3(256), 0, stream,
                       in_proj_w, Wt1, 1024, 4096);
    hipLaunchKernelGGL(transpose_bf16, dim3(1024 / 32, 2048 / 32), dim3(256), 0, stream,
                       out_proj_w, Wt6, 2048, 1024);

    // K1: xz = hs @ in_proj_w   (bf16 MFMA NT)
    hipLaunchKernelGGL(gemm_bf16_nt, dim3(4096 / 128, NROW / 128), dim3(256), 0, stream,
                       hs_bf, Wt1, xz, NROW, 4096, D_MODEL, 4096);

    // K2: depthwise conv + bias + silu -> x_bld
    {
        const int total = B_SZ * L_SEQ * D_INNER;
        hipLaunchKernelGGL(conv_silu_kernel, dim3((total + 255) / 256), dim3(256), 0, stream,
                           xz, conv_w, conv_b, x_bld);
    }
    // K3: x_dbl = x_bld @ x_proj_w   [8192,2048] @ [2048,96]  (fp32)
    {
        dim3 grid((96 + 63) / 64, NROW / 64);
        hipLaunchKernelGGL(gemm_f32, grid, dim3(256), 0, stream,
                           x_bld, x_proj_w, x_dbl, NROW, 96, D_INNER, D_INNER, 96, 96);
    }
    // K4: delta -> x-half of xz
    {
        dim3 grid(D_INNER / 256, NROW / 16);
        hipLaunchKernelGGL(dt_softplus_kernel, grid, dim3(256), 0, stream,
                           x_dbl, dt_proj_w, dt_proj_b, xz);
    }
    // K5: chunked scan (thread-local 16-state)
    {
        const int total1 = B_SZ * D_INNER * NCHUNK;          // 524,288
        hipLaunchKernelGGL(scan_pass1, dim3(total1 / 256), dim3(256), 0, stream,
                           xz, x_bld, x_dbl, A_log, hfin, Ssum);
        const int total2 = B_SZ * D_INNER * D_STATE;         // 131,072
        hipLaunchKernelGGL(scan_pass2, dim3(total2 / 256), dim3(256), 0, stream,
                           hfin, Ssum, A_log);
        hipLaunchKernelGGL(scan_pass3, dim3(total1 / 256), dim3(256), 0, stream,
                           xz, x_bld, x_dbl, A_log, D_skip, hfin);
    }
    // C1: y (x-half of xz) -> y_bf
    hipLaunchKernelGGL(convert_y_bf16, dim3(16384), dim3(256), 0, stream, xz, y_bf);

    // K6: out = y @ out_proj_w   (bf16 MFMA NT)
    hipLaunchKernelGGL(gemm_bf16_nt, dim3(1024 / 128, NROW / 128), dim3(256), 0, stream,
                       y_bf, Wt6, out, NROW, 1024, D_INNER, 1024);
}

// Round 6
// 531.090 us; speedup vs baseline: 6.7271x; 1.5567x over previous
//
#include <hip/hip_runtime.h>

#define B_SZ 4
#define L_SEQ 2048
#define D_MODEL 1024
#define D_INNER 2048
#define D_STATE 16
#define DT_RANK 64
#define NROW (B_SZ * L_SEQ)   // 8192
#define NCHUNK 64
#define CHUNK (L_SEQ / NCHUNK)  // 32
#define KSPLIT 8
#define KCH (D_INNER / KSPLIT)  // 256

typedef __bf16 bf16x8 __attribute__((ext_vector_type(8)));
typedef float  f32x4  __attribute__((ext_vector_type(4)));

__device__ __forceinline__ ushort f2bf(float f) {
    union { float f; uint32_t u; } v; v.f = f;
    const uint32_t r = (v.u + 0x7FFFu + ((v.u >> 16) & 1u)) >> 16;  // RNE
    return (ushort)r;
}

// ---------------------------------------------------------------------------
// fp32 -> bf16 flat convert (4 elems/thread)
// ---------------------------------------------------------------------------
__global__ __launch_bounds__(256) void convert_bf16_flat(
    const float* __restrict__ in, ushort* __restrict__ out, int n4)
{
    const int i = blockIdx.x * 256 + threadIdx.x;
    if (i >= n4) return;
    const float4 v = reinterpret_cast<const float4*>(in)[i];
    ushort4 o; o.x = f2bf(v.x); o.y = f2bf(v.y); o.z = f2bf(v.z); o.w = f2bf(v.w);
    reinterpret_cast<ushort4*>(out)[i] = o;
}

// ---------------------------------------------------------------------------
// W[K,N] fp32 -> Wt[N,K] bf16 (32x32 LDS tile transpose)
// ---------------------------------------------------------------------------
__global__ __launch_bounds__(256) void transpose_bf16(
    const float* __restrict__ W, ushort* __restrict__ Wt, int K, int N)
{
    __shared__ float tile[32][33];
    const int n0 = blockIdx.x * 32, k0 = blockIdx.y * 32;
    const int c = threadIdx.x & 31, r = threadIdx.x >> 5;
    #pragma unroll
    for (int p = 0; p < 4; ++p)
        tile[r + p * 8][c] = W[(size_t)(k0 + r + p * 8) * N + n0 + c];
    __syncthreads();
    #pragma unroll
    for (int p = 0; p < 4; ++p)
        Wt[(size_t)(n0 + r + p * 8) * K + k0 + c] = f2bf(tile[c][r + p * 8]);
}

// ---------------------------------------------------------------------------
// y fp32 (x-half of xz, row stride 4096) -> y_bf [8192][2048] bf16
// ---------------------------------------------------------------------------
__global__ __launch_bounds__(256) void convert_y_bf16(
    const float* __restrict__ xz, ushort* __restrict__ ybf)
{
    const int i = blockIdx.x * 256 + threadIdx.x;
    const int m = i >> 9;
    const int d4 = (i & 511) * 4;
    const float4 v = *reinterpret_cast<const float4*>(&xz[(size_t)m * 4096 + d4]);
    ushort4 o; o.x = f2bf(v.x); o.y = f2bf(v.y); o.z = f2bf(v.z); o.w = f2bf(v.w);
    *reinterpret_cast<ushort4*>(&ybf[(size_t)m * 2048 + d4]) = o;
}

// ---------------------------------------------------------------------------
// bf16 NT GEMM: C[M,N](f32) = A[M,K](bf16) * Bt[N,K](bf16)^T
// ---------------------------------------------------------------------------
__global__ __launch_bounds__(256) void gemm_bf16_nt(
    const ushort* __restrict__ A, const ushort* __restrict__ Bt,
    float* __restrict__ C, int M, int N, int K, int ldc)
{
    __shared__ ushort Alds[128][72];
    __shared__ ushort Blds[128][72];
    const int tid  = threadIdx.x;
    const int lane = tid & 63;
    const int wid  = tid >> 6;
    const int wr = wid >> 1, wc = wid & 1;
    const int m0 = blockIdx.y * 128, n0 = blockIdx.x * 128;
    const int l15 = lane & 15, l16 = lane >> 4;

    f32x4 acc[4][4] = {};

    const int sr = tid >> 1;
    const int sk = (tid & 1) * 32;

    for (int k0 = 0; k0 < K; k0 += 64) {
        const uint4* ga = reinterpret_cast<const uint4*>(A  + (size_t)(m0 + sr) * K + k0 + sk);
        const uint4* gb = reinterpret_cast<const uint4*>(Bt + (size_t)(n0 + sr) * K + k0 + sk);
        const uint4 a0 = ga[0], a1 = ga[1], a2 = ga[2], a3 = ga[3];
        const uint4 b0 = gb[0], b1 = gb[1], b2 = gb[2], b3 = gb[3];
        *reinterpret_cast<uint4*>(&Alds[sr][sk])      = a0;
        *reinterpret_cast<uint4*>(&Alds[sr][sk + 8])  = a1;
        *reinterpret_cast<uint4*>(&Alds[sr][sk + 16]) = a2;
        *reinterpret_cast<uint4*>(&Alds[sr][sk + 24]) = a3;
        *reinterpret_cast<uint4*>(&Blds[sr][sk])      = b0;
        *reinterpret_cast<uint4*>(&Blds[sr][sk + 8])  = b1;
        *reinterpret_cast<uint4*>(&Blds[sr][sk + 16]) = b2;
        *reinterpret_cast<uint4*>(&Blds[sr][sk + 24]) = b3;
        __syncthreads();
        #pragma unroll
        for (int ks = 0; ks < 64; ks += 32) {
            bf16x8 af[4], bfr[4];
            #pragma unroll
            for (int mi = 0; mi < 4; ++mi)
                af[mi] = *reinterpret_cast<const bf16x8*>(&Alds[wr * 64 + mi * 16 + l15][ks + l16 * 8]);
            #pragma unroll
            for (int ni = 0; ni < 4; ++ni)
                bfr[ni] = *reinterpret_cast<const bf16x8*>(&Blds[wc * 64 + ni * 16 + l15][ks + l16 * 8]);
            #pragma unroll
            for (int mi = 0; mi < 4; ++mi)
                #pragma unroll
                for (int ni = 0; ni < 4; ++ni)
                    acc[mi][ni] = __builtin_amdgcn_mfma_f32_16x16x32_bf16(af[mi], bfr[ni], acc[mi][ni], 0, 0, 0);
        }
        __syncthreads();
    }

    #pragma unroll
    for (int mi = 0; mi < 4; ++mi) {
        const int mrow = m0 + wr * 64 + mi * 16 + l16 * 4;
        #pragma unroll
        for (int ni = 0; ni < 4; ++ni) {
            const int ncol = n0 + wc * 64 + ni * 16 + l15;
            #pragma unroll
            for (int r = 0; r < 4; ++r)
                C[(size_t)(mrow + r) * ldc + ncol] = acc[mi][ni][r];
        }
    }
}

// ---------------------------------------------------------------------------
// K3a: x_proj split-K partial GEMM.
// part[ks][m][96] = x_bld[m, ks*256:(ks+1)*256] @ W[ks*256:(ks+1)*256, 0:96]
// Block: 256 thr, 64 rows x full 96 cols; 4x6 micro-tile per thread.
// Grid: (128 m-blocks, 8 k-splits) = 1024 blocks -> ~16 waves/CU.
// ---------------------------------------------------------------------------
__global__ __launch_bounds__(256) void xproj_partial(
    const float* __restrict__ A, const float* __restrict__ W,
    float* __restrict__ part)
{
    const int m0 = blockIdx.x * 64;
    const int k0 = blockIdx.y * KCH;
    const int tid = threadIdx.x;
    const int tx = tid & 15;     // col group: cols tx*6 .. tx*6+5
    const int ty = tid >> 4;     // row group: rows ty*4 .. ty*4+3

    __shared__ float As[16][68];
    __shared__ float Ws[16][96];

    float c[4][6] = {};

    for (int kt = 0; kt < KCH; kt += 16) {
        {
            const int ka = tid & 15, ma = tid >> 4;
            #pragma unroll
            for (int p = 0; p < 4; ++p)
                As[ka][ma + p * 16] = A[(size_t)(m0 + ma + p * 16) * D_INNER + k0 + kt + ka];
        }
        {
            const int kr = tid >> 4;
            const int nc = (tid & 15) * 6;
            #pragma unroll
            for (int j = 0; j < 6; ++j)
                Ws[kr][nc + j] = W[(size_t)(k0 + kt + kr) * 96 + nc + j];
        }
        __syncthreads();
        #pragma unroll
        for (int kk = 0; kk < 16; ++kk) {
            const float4 av = *reinterpret_cast<const float4*>(&As[kk][ty * 4]);
            const float a[4] = {av.x, av.y, av.z, av.w};
            float w[6];
            #pragma unroll
            for (int j = 0; j < 6; ++j) w[j] = Ws[kk][tx * 6 + j];
            #pragma unroll
            for (int i = 0; i < 4; ++i)
                #pragma unroll
                for (int j = 0; j < 6; ++j)
                    c[i][j] = fmaf(a[i], w[j], c[i][j]);
        }
        __syncthreads();
    }

    #pragma unroll
    for (int i = 0; i < 4; ++i) {
        const int m = m0 + ty * 4 + i;
        #pragma unroll
        for (int j = 0; j < 6; ++j)
            part[((size_t)blockIdx.y * NROW + m) * 96 + tx * 6 + j] = c[i][j];
    }
}

// K3b: x_dbl = sum over 8 k-splits (fixed order -> deterministic)
__global__ __launch_bounds__(256) void xproj_reduce(
    const float* __restrict__ part, float* __restrict__ x_dbl)
{
    const int i = blockIdx.x * 256 + threadIdx.x;   // float4 group
    if (i >= NROW * 96 / 4) return;
    const float4* p4 = reinterpret_cast<const float4*>(part);
    const size_t stride = (size_t)NROW * 96 / 4;
    float4 s = p4[i];
    #pragma unroll
    for (int ks = 1; ks < KSPLIT; ++ks) {
        const float4 v = p4[(size_t)ks * stride + i];
        s.x += v.x; s.y += v.y; s.z += v.z; s.w += v.w;
    }
    reinterpret_cast<float4*>(x_dbl)[i] = s;
}

// ---------------------------------------------------------------------------
// Depthwise conv (taps x[t-6..t-3]) + bias + SiLU.
// ---------------------------------------------------------------------------
__global__ __launch_bounds__(256) void conv_silu_kernel(
    const float* __restrict__ xz, const float* __restrict__ conv_w,
    const float* __restrict__ conv_b, float* __restrict__ x_bld)
{
    const int idx = blockIdx.x * 256 + threadIdx.x;
    if (idx >= B_SZ * L_SEQ * D_INNER) return;
    const int d = idx & (D_INNER - 1);
    const int t = (idx >> 11) & (L_SEQ - 1);
    const int b = idx >> 22;

    const float4 w = *reinterpret_cast<const float4*>(&conv_w[d * 4]);
    const float wk[4] = {w.x, w.y, w.z, w.w};
    float acc = conv_b[d];
    const size_t rowbase = (size_t)b * L_SEQ * 4096 + d;
    #pragma unroll
    for (int k = 0; k < 4; ++k) {
        const int tt = t - 6 + k;
        if (tt >= 0) acc = fmaf(wk[k], xz[rowbase + (size_t)tt * 4096], acc);
    }
    const float s = acc / (1.f + __expf(-acc));
    x_bld[idx] = s;
}

// ---------------------------------------------------------------------------
// delta = softplus(dt_low @ dt_proj_w + 2*bias) -> x-half of xz (stride 4096)
// ---------------------------------------------------------------------------
__global__ __launch_bounds__(256) void dt_softplus_kernel(
    const float* __restrict__ x_dbl, const float* __restrict__ W,
    const float* __restrict__ bias, float* __restrict__ delta_xz)
{
    __shared__ float a[16][64];
    const int tid = threadIdx.x;
    const int m0 = blockIdx.y * 16;
    const int d = blockIdx.x * 256 + tid;

    {
        const int r = tid & 63, i = tid >> 6;
        #pragma unroll
        for (int p = 0; p < 4; ++p)
            a[i + p * 4][r] = x_dbl[(size_t)(m0 + i + p * 4) * 96 + r];
    }
    __syncthreads();

    float acc[16] = {};
    for (int r = 0; r < 64; ++r) {
        const float w = W[(size_t)r * D_INNER + d];
        #pragma unroll
        for (int mi = 0; mi < 16; ++mi) acc[mi] = fmaf(a[mi][r], w, acc[mi]);
    }
    const float b2 = 2.0f * bias[d];
    #pragma unroll
    for (int mi = 0; mi < 16; ++mi) {
        const float v = acc[mi] + b2;
        const float sp = (v > 20.0f) ? v : log1pf(__expf(v));
        delta_xz[(size_t)(m0 + mi) * 4096 + d] = sp;
    }
}

// ---------------------------------------------------------------------------
// Chunked parallel scan, thread-local 16-state version (see round 4 notes).
// ---------------------------------------------------------------------------
__global__ __launch_bounds__(256) void scan_pass1(
    const float* __restrict__ xz, const float* __restrict__ u_,
    const float* __restrict__ x_dbl, const float* __restrict__ A_log,
    float* __restrict__ hfin, float* __restrict__ Ssum)
{
    const int g = blockIdx.x * 256 + threadIdx.x;  // 0 .. 524287
    const int d = g & (D_INNER - 1);
    const int b = (g >> 11) & 3;
    const int c = g >> 13;

    float A[D_STATE];
    #pragma unroll
    for (int q = 0; q < 4; ++q) {
        const float4 al = *reinterpret_cast<const float4*>(&A_log[d * D_STATE + q * 4]);
        A[q * 4 + 0] = -__expf(al.x); A[q * 4 + 1] = -__expf(al.y);
        A[q * 4 + 2] = -__expf(al.z); A[q * 4 + 3] = -__expf(al.w);
    }

    const int t0 = c * CHUNK;
    const size_t base4096 = (size_t)b * L_SEQ * 4096 + d;
    const size_t base2048 = (size_t)b * L_SEQ * D_INNER + d;
    const size_t base96   = (size_t)b * L_SEQ * 96;

    float h[D_STATE] = {};
    float S = 0.f;
    for (int i = 0; i < CHUNK; ++i) {
        const int t = t0 + i;
        const float dv = xz[base4096 + (size_t)t * 4096];   // delta
        const float uv = u_[base2048 + (size_t)t * D_INNER];
        float Bv[D_STATE];
        #pragma unroll
        for (int q = 0; q < 4; ++q)
            *reinterpret_cast<float4*>(&Bv[q * 4]) =
                *reinterpret_cast<const float4*>(&x_dbl[base96 + (size_t)t * 96 + DT_RANK + q * 4]);
        const float du = dv * uv;
        S += dv;
        #pragma unroll
        for (int n = 0; n < D_STATE; ++n)
            h[n] = fmaf(h[n], __expf(dv * A[n]), du * Bv[n]);
    }
    const size_t sidx = (size_t)(c * B_SZ + b) * D_INNER + d;
    #pragma unroll
    for (int q = 0; q < 4; ++q)
        *reinterpret_cast<float4*>(&hfin[sidx * D_STATE + q * 4]) =
            *reinterpret_cast<const float4*>(&h[q * 4]);
    Ssum[sidx] = S;
}

__global__ __launch_bounds__(256) void scan_pass2(
    float* __restrict__ hfin, const float* __restrict__ Ssum,
    const float* __restrict__ A_log)
{
    const int g = blockIdx.x * 256 + threadIdx.x;  // 0 .. 131071
    const int n = g & 15;
    const int d = (g >> 4) & (D_INNER - 1);
    const int b = g >> 15;
    const float A = -__expf(A_log[d * D_STATE + n]);

    float H = 0.f;
    #pragma unroll 4
    for (int c = 0; c < NCHUNK; ++c) {
        const size_t sidx = (size_t)(c * B_SZ + b) * D_INNER + d;
        const float P = __expf(A * Ssum[sidx]);
        const float hc = hfin[sidx * D_STATE + n];
        hfin[sidx * D_STATE + n] = H;       // Hinit in place
        H = fmaf(H, P, hc);
    }
}

__global__ __launch_bounds__(256) void scan_pass3(
    float* xz, const float* __restrict__ u_,
    const float* __restrict__ x_dbl, const float* __restrict__ A_log,
    const float* __restrict__ D_skip, const float* __restrict__ Hinit)
{
    const int g = blockIdx.x * 256 + threadIdx.x;  // 0 .. 524287
    const int d = g & (D_INNER - 1);
    const int b = (g >> 11) & 3;
    const int c = g >> 13;

    float A[D_STATE];
    #pragma unroll
    for (int q = 0; q < 4; ++q) {
        const float4 al = *reinterpret_cast<const float4*>(&A_log[d * D_STATE + q * 4]);
        A[q * 4 + 0] = -__expf(al.x); A[q * 4 + 1] = -__expf(al.y);
        A[q * 4 + 2] = -__expf(al.z); A[q * 4 + 3] = -__expf(al.w);
    }
    const float Dd = D_skip[d];

    const int t0 = c * CHUNK;
    const size_t base4096 = (size_t)b * L_SEQ * 4096;
    const size_t base2048 = (size_t)b * L_SEQ * D_INNER + d;
    const size_t base96   = (size_t)b * L_SEQ * 96;

    float h[D_STATE];
    const size_t sidx = (size_t)(c * B_SZ + b) * D_INNER + d;
    #pragma unroll
    for (int q = 0; q < 4; ++q)
        *reinterpret_cast<float4*>(&h[q * 4]) =
            *reinterpret_cast<const float4*>(&Hinit[sidx * D_STATE + q * 4]);

    for (int i = 0; i < CHUNK; ++i) {
        const int t = t0 + i;
        const float dv = xz[base4096 + (size_t)t * 4096 + d];           // delta
        const float uv = u_[base2048 + (size_t)t * D_INNER];
        const float zv = xz[base4096 + (size_t)t * 4096 + D_INNER + d];
        float Bv[D_STATE], Cv[D_STATE];
        #pragma unroll
        for (int q = 0; q < 4; ++q) {
            *reinterpret_cast<float4*>(&Bv[q * 4]) =
                *reinterpret_cast<const float4*>(&x_dbl[base96 + (size_t)t * 96 + DT_RANK + q * 4]);
            *reinterpret_cast<float4*>(&Cv[q * 4]) =
                *reinterpret_cast<const float4*>(&x_dbl[base96 + (size_t)t * 96 + DT_RANK + D_STATE + q * 4]);
        }
        const float du = dv * uv;
        float y = 0.f;
        #pragma unroll
        for (int n = 0; n < D_STATE; ++n) {
            h[n] = fmaf(h[n], __expf(dv * A[n]), du * Bv[n]);
            y = fmaf(h[n], Cv[n], y);
        }
        const float sig = 1.f / (1.f + __expf(-zv));
        const float yv = (y + uv * Dd) * (zv * sig);
        xz[base4096 + (size_t)t * 4096 + d] = yv;                       // y over delta
    }
}

// ---------------------------------------------------------------------------
extern "C" void kernel_launch(void* const* d_in, const int* in_sizes, int n_in,
                              void* d_out, int out_size, void* d_ws, size_t ws_size,
                              hipStream_t stream)
{
    const float* hs         = (const float*)d_in[0];
    const float* in_proj_w  = (const float*)d_in[1];
    const float* conv_w     = (const float*)d_in[2];
    const float* conv_b     = (const float*)d_in[3];
    const float* x_proj_w   = (const float*)d_in[4];
    const float* dt_proj_w  = (const float*)d_in[5];
    const float* dt_proj_b  = (const float*)d_in[6];
    const float* A_log      = (const float*)d_in[7];
    const float* D_skip     = (const float*)d_in[8];
    const float* out_proj_w = (const float*)d_in[9];
    float* out = (float*)d_out;

    // Workspace (f32 elems), total 61,079,552 f32 = 244.3 MB:
    //   xz     134.2 MB  x-half reused: x -> delta -> y
    //   x_bld   67.1 MB
    //   x_dbl    3.1 MB
    //   R1      35.7 MB  time-multiplexed:
    //            phase A (C0/K1): hs_bf 16.8 + Wt1 8.4
    //            phase B (K3):    part 25.2
    //            phase C (K5):    hfin 33.5 + Ssum 2.1
    //            phase D (C1/K6): y_bf 33.5
    //   Wt6      4.2 MB
    float* ws    = (float*)d_ws;
    float* xz    = ws;
    float* x_bld = xz + (size_t)NROW * 4096;
    float* x_dbl = x_bld + (size_t)NROW * 2048;
    float* R1    = x_dbl + (size_t)NROW * 96;
    float* wt6f  = R1 + 8912896;

    ushort* hs_bf = (ushort*)R1;
    ushort* Wt1   = (ushort*)(R1 + 4194304);
    float*  part  = R1;                                // KSPLIT*NROW*96 f32
    float*  hfin  = R1;
    float*  Ssum  = R1 + 8388608;
    ushort* y_bf  = (ushort*)R1;
    ushort* Wt6   = (ushort*)wt6f;

    // C0: converts (hs flat; weights transposed to [N,K] bf16)
    hipLaunchKernelGGL(convert_bf16_flat, dim3(8192), dim3(256), 0, stream,
                       hs, hs_bf, NROW * D_MODEL / 4);
    hipLaunchKernelGGL(transpose_bf16, dim3(4096 / 32, 1024 / 32), dim3(256), 0, stream,
                       in_proj_w, Wt1, 1024, 4096);
    hipLaunchKernelGGL(transpose_bf16, dim3(1024 / 32, 2048 / 32), dim3(256), 0, stream,
                       out_proj_w, Wt6, 2048, 1024);

    // K1: xz = hs @ in_proj_w   (bf16 MFMA NT)
    hipLaunchKernelGGL(gemm_bf16_nt, dim3(4096 / 128, NROW / 128), dim3(256), 0, stream,
                       hs_bf, Wt1, xz, NROW, 4096, D_MODEL, 4096);

    // K2: depthwise conv + bias + silu -> x_bld
    {
        const int total = B_SZ * L_SEQ * D_INNER;
        hipLaunchKernelGGL(conv_silu_kernel, dim3((total + 255) / 256), dim3(256), 0, stream,
                           xz, conv_w, conv_b, x_bld);
    }
    // K3: x_dbl = x_bld @ x_proj_w  (split-K fp32, 1024 blocks)
    {
        hipLaunchKernelGGL(xproj_partial, dim3(NROW / 64, KSPLIT), dim3(256), 0, stream,
                           x_bld, x_proj_w, part);
        hipLaunchKernelGGL(xproj_reduce, dim3(NROW * 96 / 4 / 256), dim3(256), 0, stream,
                           part, x_dbl);
    }
    // K4: delta -> x-half of xz
    {
        dim3 grid(D_INNER / 256, NROW / 16);
        hipLaunchKernelGGL(dt_softplus_kernel, grid, dim3(256), 0, stream,
                           x_dbl, dt_proj_w, dt_proj_b, xz);
    }
    // K5: chunked scan (thread-local 16-state)
    {
        const int total1 = B_SZ * D_INNER * NCHUNK;          // 524,288
        hipLaunchKernelGGL(scan_pass1, dim3(total1 / 256), dim3(256), 0, stream,
                           xz, x_bld, x_dbl, A_log, hfin, Ssum);
        const int total2 = B_SZ * D_INNER * D_STATE;         // 131,072
        hipLaunchKernelGGL(scan_pass2, dim3(total2 / 256), dim3(256), 0, stream,
                           hfin, Ssum, A_log);
        hipLaunchKernelGGL(scan_pass3, dim3(total1 / 256), dim3(256), 0, stream,
                           xz, x_bld, x_dbl, A_log, D_skip, hfin);
    }
    // C1: y (x-half of xz) -> y_bf
    hipLaunchKernelGGL(convert_y_bf16, dim3(16384), dim3(256), 0, stream, xz, y_bf);

    // K6: out = y @ out_proj_w   (bf16 MFMA NT)
    hipLaunchKernelGGL(gemm_bf16_nt, dim3(1024 / 128, NROW / 128), dim3(256), 0, stream,
                       y_bf, Wt6, out, NROW, 1024, D_INNER, 1024);
}

// Round 7
// 529.975 us; speedup vs baseline: 6.7412x; 1.0021x over previous
//
#include <hip/hip_runtime.h>

#define B_SZ 4
#define L_SEQ 2048
#define D_MODEL 1024
#define D_INNER 2048
#define D_STATE 16
#define DT_RANK 64
#define NROW (B_SZ * L_SEQ)   // 8192
#define NCHUNK 64
#define CHUNK (L_SEQ / NCHUNK)  // 32
#define KSPLIT 8
#define KCH (D_INNER / KSPLIT)  // 256

typedef __bf16 bf16x8 __attribute__((ext_vector_type(8)));
typedef float  f32x4  __attribute__((ext_vector_type(4)));

__device__ __forceinline__ ushort f2bf(float f) {
    union { float f; uint32_t u; } v; v.f = f;
    const uint32_t r = (v.u + 0x7FFFu + ((v.u >> 16) & 1u)) >> 16;  // RNE
    return (ushort)r;
}
__device__ __forceinline__ float bf2f(ushort u) {
    union { uint32_t u; float f; } v; v.u = ((uint32_t)u) << 16;
    return v.f;
}

// async global->LDS, 16 bytes per lane (dest = wave-uniform base + lane*16)
__device__ __forceinline__ void gload16(const void* g, void* l) {
    __builtin_amdgcn_global_load_lds(
        (const __attribute__((address_space(1))) unsigned int*)g,
        (__attribute__((address_space(3))) unsigned int*)l, 16, 0, 0);
}

// ---------------------------------------------------------------------------
// fp32 -> bf16 flat convert (4 elems/thread)
// ---------------------------------------------------------------------------
__global__ __launch_bounds__(256) void convert_bf16_flat(
    const float* __restrict__ in, ushort* __restrict__ out, int n4)
{
    const int i = blockIdx.x * 256 + threadIdx.x;
    if (i >= n4) return;
    const float4 v = reinterpret_cast<const float4*>(in)[i];
    ushort4 o; o.x = f2bf(v.x); o.y = f2bf(v.y); o.z = f2bf(v.z); o.w = f2bf(v.w);
    reinterpret_cast<ushort4*>(out)[i] = o;
}

// ---------------------------------------------------------------------------
// W[K,N] fp32 -> Wt[N,K] bf16 (32x32 LDS tile transpose)
// ---------------------------------------------------------------------------
__global__ __launch_bounds__(256) void transpose_bf16(
    const float* __restrict__ W, ushort* __restrict__ Wt, int K, int N)
{
    __shared__ float tile[32][33];
    const int n0 = blockIdx.x * 32, k0 = blockIdx.y * 32;
    const int c = threadIdx.x & 31, r = threadIdx.x >> 5;
    #pragma unroll
    for (int p = 0; p < 4; ++p)
        tile[r + p * 8][c] = W[(size_t)(k0 + r + p * 8) * N + n0 + c];
    __syncthreads();
    #pragma unroll
    for (int p = 0; p < 4; ++p)
        Wt[(size_t)(n0 + r + p * 8) * K + k0 + c] = f2bf(tile[c][r + p * 8]);
}

// ---------------------------------------------------------------------------
// bf16 NT GEMM (m97 structure): C[M,N] = A[M,K] * Bt[N,K]^T
// 128x128 tile, BK=64, linear LDS, global_load_lds 16B staging.
// EPI=0: plain fp32 C (ldc).
// EPI=1: mamba in_proj epilogue — cols <2048 write fp32 x[M][2048];
//        cols >=2048 write bf16 silu(z) to Cz[M][2048].
// ---------------------------------------------------------------------------
template <int EPI>
__global__ __launch_bounds__(256) void gemm_bf16_nt(
    const ushort* __restrict__ A, const ushort* __restrict__ Bt,
    float* __restrict__ C, ushort* __restrict__ Cz, int M, int N, int K, int ldc)
{
    __shared__ ushort Alds[128][64];
    __shared__ ushort Blds[128][64];
    const int tid  = threadIdx.x;
    const int lane = tid & 63;
    const int wid  = tid >> 6;
    const int wr = wid >> 1, wc = wid & 1;
    const int m0 = blockIdx.y * 128, n0 = blockIdx.x * 128;
    const int l15 = lane & 15, l16 = lane >> 4;

    f32x4 acc[4][4] = {};

    // staging: thread tid loads 16B from row (i*32 + tid/8), col (tid%8)*8
    const int strow = tid >> 3;
    const int stcol = (tid & 7) * 8;

    for (int k0 = 0; k0 < K; k0 += 64) {
        const ushort* gA = A  + (size_t)(m0 + strow) * K + k0 + stcol;
        const ushort* gB = Bt + (size_t)(n0 + strow) * K + k0 + stcol;
        ushort* lA = &Alds[0][0] + tid * 8;
        ushort* lB = &Blds[0][0] + tid * 8;
        #pragma unroll
        for (int i = 0; i < 4; ++i) {
            gload16(gA + (size_t)i * 32 * K, lA + i * 2048);
            gload16(gB + (size_t)i * 32 * K, lB + i * 2048);
        }
        __syncthreads();  // compiler emits vmcnt(0) drain here
        #pragma unroll
        for (int ks = 0; ks < 64; ks += 32) {
            bf16x8 af[4], bfr[4];
            #pragma unroll
            for (int mi = 0; mi < 4; ++mi)
                af[mi] = *reinterpret_cast<const bf16x8*>(&Alds[wr * 64 + mi * 16 + l15][ks + l16 * 8]);
            #pragma unroll
            for (int ni = 0; ni < 4; ++ni)
                bfr[ni] = *reinterpret_cast<const bf16x8*>(&Blds[wc * 64 + ni * 16 + l15][ks + l16 * 8]);
            #pragma unroll
            for (int mi = 0; mi < 4; ++mi)
                #pragma unroll
                for (int ni = 0; ni < 4; ++ni)
                    acc[mi][ni] = __builtin_amdgcn_mfma_f32_16x16x32_bf16(af[mi], bfr[ni], acc[mi][ni], 0, 0, 0);
        }
        __syncthreads();
    }

    #pragma unroll
    for (int mi = 0; mi < 4; ++mi) {
        const int mrow = m0 + wr * 64 + mi * 16 + l16 * 4;
        #pragma unroll
        for (int ni = 0; ni < 4; ++ni) {
            const int ncol = n0 + wc * 64 + ni * 16 + l15;
            #pragma unroll
            for (int r = 0; r < 4; ++r) {
                const float v = acc[mi][ni][r];
                if (EPI == 0) {
                    C[(size_t)(mrow + r) * ldc + ncol] = v;
                } else {
                    if (n0 < 2048) {
                        C[(size_t)(mrow + r) * 2048 + ncol] = v;       // x (fp32)
                    } else {
                        const float s = v / (1.f + __expf(-v));        // silu(z)
                        Cz[(size_t)(mrow + r) * 2048 + (ncol - 2048)] = f2bf(s);
                    }
                }
            }
        }
    }
}

// ---------------------------------------------------------------------------
// K3a: x_proj split-K partial GEMM (N=96, fp32).
// ---------------------------------------------------------------------------
__global__ __launch_bounds__(256) void xproj_partial(
    const float* __restrict__ A, const float* __restrict__ W,
    float* __restrict__ part)
{
    const int m0 = blockIdx.x * 64;
    const int k0 = blockIdx.y * KCH;
    const int tid = threadIdx.x;
    const int tx = tid & 15;
    const int ty = tid >> 4;

    __shared__ float As[16][68];
    __shared__ float Ws[16][96];

    float c[4][6] = {};

    for (int kt = 0; kt < KCH; kt += 16) {
        {
            const int ka = tid & 15, ma = tid >> 4;
            #pragma unroll
            for (int p = 0; p < 4; ++p)
                As[ka][ma + p * 16] = A[(size_t)(m0 + ma + p * 16) * D_INNER + k0 + kt + ka];
        }
        {
            const int kr = tid >> 4;
            const int nc = (tid & 15) * 6;
            #pragma unroll
            for (int j = 0; j < 6; ++j)
                Ws[kr][nc + j] = W[(size_t)(k0 + kt + kr) * 96 + nc + j];
        }
        __syncthreads();
        #pragma unroll
        for (int kk = 0; kk < 16; ++kk) {
            const float4 av = *reinterpret_cast<const float4*>(&As[kk][ty * 4]);
            const float a[4] = {av.x, av.y, av.z, av.w};
            float w[6];
            #pragma unroll
            for (int j = 0; j < 6; ++j) w[j] = Ws[kk][tx * 6 + j];
            #pragma unroll
            for (int i = 0; i < 4; ++i)
                #pragma unroll
                for (int j = 0; j < 6; ++j)
                    c[i][j] = fmaf(a[i], w[j], c[i][j]);
        }
        __syncthreads();
    }

    #pragma unroll
    for (int i = 0; i < 4; ++i) {
        const int m = m0 + ty * 4 + i;
        #pragma unroll
        for (int j = 0; j < 6; ++j)
            part[((size_t)blockIdx.y * NROW + m) * 96 + tx * 6 + j] = c[i][j];
    }
}

__global__ __launch_bounds__(256) void xproj_reduce(
    const float* __restrict__ part, float* __restrict__ x_dbl)
{
    const int i = blockIdx.x * 256 + threadIdx.x;
    if (i >= NROW * 96 / 4) return;
    const float4* p4 = reinterpret_cast<const float4*>(part);
    const size_t stride = (size_t)NROW * 96 / 4;
    float4 s = p4[i];
    #pragma unroll
    for (int ks = 1; ks < KSPLIT; ++ks) {
        const float4 v = p4[(size_t)ks * stride + i];
        s.x += v.x; s.y += v.y; s.z += v.z; s.w += v.w;
    }
    reinterpret_cast<float4*>(x_dbl)[i] = s;
}

// ---------------------------------------------------------------------------
// Depthwise conv (taps x[t-6..t-3]) + bias + SiLU.  x is [NROW][2048] fp32.
// ---------------------------------------------------------------------------
__global__ __launch_bounds__(256) void conv_silu_kernel(
    const float* __restrict__ x, const float* __restrict__ conv_w,
    const float* __restrict__ conv_b, float* __restrict__ x_bld)
{
    const int idx = blockIdx.x * 256 + threadIdx.x;
    if (idx >= B_SZ * L_SEQ * D_INNER) return;
    const int d = idx & (D_INNER - 1);
    const int t = (idx >> 11) & (L_SEQ - 1);
    const int b = idx >> 22;

    const float4 w = *reinterpret_cast<const float4*>(&conv_w[d * 4]);
    const float wk[4] = {w.x, w.y, w.z, w.w};
    float acc = conv_b[d];
    const size_t rowbase = (size_t)b * L_SEQ * D_INNER + d;
    #pragma unroll
    for (int k = 0; k < 4; ++k) {
        const int tt = t - 6 + k;
        if (tt >= 0) acc = fmaf(wk[k], x[rowbase + (size_t)tt * D_INNER], acc);
    }
    const float s = acc / (1.f + __expf(-acc));
    x_bld[idx] = s;
}

// ---------------------------------------------------------------------------
// delta = softplus(dt_low @ dt_proj_w + 2*bias) -> delta[M][2048] (over x)
// ---------------------------------------------------------------------------
__global__ __launch_bounds__(256) void dt_softplus_kernel(
    const float* __restrict__ x_dbl, const float* __restrict__ W,
    const float* __restrict__ bias, float* __restrict__ delta)
{
    __shared__ float a[16][64];
    const int tid = threadIdx.x;
    const int m0 = blockIdx.y * 16;
    const int d = blockIdx.x * 256 + tid;

    {
        const int r = tid & 63, i = tid >> 6;
        #pragma unroll
        for (int p = 0; p < 4; ++p)
            a[i + p * 4][r] = x_dbl[(size_t)(m0 + i + p * 4) * 96 + r];
    }
    __syncthreads();

    float acc[16] = {};
    for (int r = 0; r < 64; ++r) {
        const float w = W[(size_t)r * D_INNER + d];
        #pragma unroll
        for (int mi = 0; mi < 16; ++mi) acc[mi] = fmaf(a[mi][r], w, acc[mi]);
    }
    const float b2 = 2.0f * bias[d];
    #pragma unroll
    for (int mi = 0; mi < 16; ++mi) {
        const float v = acc[mi] + b2;
        const float sp = (v > 20.0f) ? v : log1pf(__expf(v));
        delta[(size_t)(m0 + mi) * D_INNER + d] = sp;
    }
}

// ---------------------------------------------------------------------------
// Chunked parallel scan, thread-local 16-state (see round 4/5 notes).
// delta and u are both [NROW][2048] fp32 now.
// ---------------------------------------------------------------------------
__global__ __launch_bounds__(256) void scan_pass1(
    const float* __restrict__ delta, const float* __restrict__ u_,
    const float* __restrict__ x_dbl, const float* __restrict__ A_log,
    float* __restrict__ hfin, float* __restrict__ Ssum)
{
    const int g = blockIdx.x * 256 + threadIdx.x;  // 0 .. 524287
    const int d = g & (D_INNER - 1);
    const int b = (g >> 11) & 3;
    const int c = g >> 13;

    float A[D_STATE];
    #pragma unroll
    for (int q = 0; q < 4; ++q) {
        const float4 al = *reinterpret_cast<const float4*>(&A_log[d * D_STATE + q * 4]);
        A[q * 4 + 0] = -__expf(al.x); A[q * 4 + 1] = -__expf(al.y);
        A[q * 4 + 2] = -__expf(al.z); A[q * 4 + 3] = -__expf(al.w);
    }

    const int t0 = c * CHUNK;
    const size_t base2048 = (size_t)b * L_SEQ * D_INNER + d;
    const size_t base96   = (size_t)b * L_SEQ * 96;

    float h[D_STATE] = {};
    float S = 0.f;
    for (int i = 0; i < CHUNK; ++i) {
        const int t = t0 + i;
        const float dv = delta[base2048 + (size_t)t * D_INNER];
        const float uv = u_[base2048 + (size_t)t * D_INNER];
        float Bv[D_STATE];
        #pragma unroll
        for (int q = 0; q < 4; ++q)
            *reinterpret_cast<float4*>(&Bv[q * 4]) =
                *reinterpret_cast<const float4*>(&x_dbl[base96 + (size_t)t * 96 + DT_RANK + q * 4]);
        const float du = dv * uv;
        S += dv;
        #pragma unroll
        for (int n = 0; n < D_STATE; ++n)
            h[n] = fmaf(h[n], __expf(dv * A[n]), du * Bv[n]);
    }
    const size_t sidx = (size_t)(c * B_SZ + b) * D_INNER + d;
    #pragma unroll
    for (int q = 0; q < 4; ++q)
        *reinterpret_cast<float4*>(&hfin[sidx * D_STATE + q * 4]) =
            *reinterpret_cast<const float4*>(&h[q * 4]);
    Ssum[sidx] = S;
}

__global__ __launch_bounds__(256) void scan_pass2(
    float* __restrict__ hfin, const float* __restrict__ Ssum,
    const float* __restrict__ A_log)
{
    const int g = blockIdx.x * 256 + threadIdx.x;  // 0 .. 131071
    const int n = g & 15;
    const int d = (g >> 4) & (D_INNER - 1);
    const int b = g >> 15;
    const float A = -__expf(A_log[d * D_STATE + n]);

    float H = 0.f;
    #pragma unroll 4
    for (int c = 0; c < NCHUNK; ++c) {
        const size_t sidx = (size_t)(c * B_SZ + b) * D_INNER + d;
        const float P = __expf(A * Ssum[sidx]);
        const float hc = hfin[sidx * D_STATE + n];
        hfin[sidx * D_STATE + n] = H;       // Hinit in place
        H = fmaf(H, P, hc);
    }
}

__global__ __launch_bounds__(256) void scan_pass3(
    const float* __restrict__ delta, const float* __restrict__ u_,
    const ushort* __restrict__ z_silu, const float* __restrict__ x_dbl,
    const float* __restrict__ A_log, const float* __restrict__ D_skip,
    const float* __restrict__ Hinit, ushort* __restrict__ y_bf)
{
    const int g = blockIdx.x * 256 + threadIdx.x;  // 0 .. 524287
    const int d = g & (D_INNER - 1);
    const int b = (g >> 11) & 3;
    const int c = g >> 13;

    float A[D_STATE];
    #pragma unroll
    for (int q = 0; q < 4; ++q) {
        const float4 al = *reinterpret_cast<const float4*>(&A_log[d * D_STATE + q * 4]);
        A[q * 4 + 0] = -__expf(al.x); A[q * 4 + 1] = -__expf(al.y);
        A[q * 4 + 2] = -__expf(al.z); A[q * 4 + 3] = -__expf(al.w);
    }
    const float Dd = D_skip[d];

    const int t0 = c * CHUNK;
    const size_t base2048 = (size_t)b * L_SEQ * D_INNER + d;
    const size_t base96   = (size_t)b * L_SEQ * 96;

    float h[D_STATE];
    const size_t sidx = (size_t)(c * B_SZ + b) * D_INNER + d;
    #pragma unroll
    for (int q = 0; q < 4; ++q)
        *reinterpret_cast<float4*>(&h[q * 4]) =
            *reinterpret_cast<const float4*>(&Hinit[sidx * D_STATE + q * 4]);

    for (int i = 0; i < CHUNK; ++i) {
        const int t = t0 + i;
        const size_t off = base2048 + (size_t)t * D_INNER;
        const float dv = delta[off];
        const float uv = u_[off];
        const float zs = bf2f(z_silu[off]);
        float Bv[D_STATE], Cv[D_STATE];
        #pragma unroll
        for (int q = 0; q < 4; ++q) {
            *reinterpret_cast<float4*>(&Bv[q * 4]) =
                *reinterpret_cast<const float4*>(&x_dbl[base96 + (size_t)t * 96 + DT_RANK + q * 4]);
            *reinterpret_cast<float4*>(&Cv[q * 4]) =
                *reinterpret_cast<const float4*>(&x_dbl[base96 + (size_t)t * 96 + DT_RANK + D_STATE + q * 4]);
        }
        const float du = dv * uv;
        float y = 0.f;
        #pragma unroll
        for (int n = 0; n < D_STATE; ++n) {
            h[n] = fmaf(h[n], __expf(dv * A[n]), du * Bv[n]);
            y = fmaf(h[n], Cv[n], y);
        }
        const float yv = (y + uv * Dd) * zs;
        y_bf[off] = f2bf(yv);
    }
}

// ---------------------------------------------------------------------------
extern "C" void kernel_launch(void* const* d_in, const int* in_sizes, int n_in,
                              void* d_out, int out_size, void* d_ws, size_t ws_size,
                              hipStream_t stream)
{
    const float* hs         = (const float*)d_in[0];
    const float* in_proj_w  = (const float*)d_in[1];
    const float* conv_w     = (const float*)d_in[2];
    const float* conv_b     = (const float*)d_in[3];
    const float* x_proj_w   = (const float*)d_in[4];
    const float* dt_proj_w  = (const float*)d_in[5];
    const float* dt_proj_b  = (const float*)d_in[6];
    const float* A_log      = (const float*)d_in[7];
    const float* D_skip     = (const float*)d_in[8];
    const float* out_proj_w = (const float*)d_in[9];
    float* out = (float*)d_out;

    // Workspace (f32 elems), total 61,079,552 f32 = 244.3 MB (known-good size):
    //   regA   67.1 MB  x_f32 [8192][2048] -> (dead after conv) delta
    //   x_bld  67.1 MB
    //   x_dbl   3.1 MB
    //   R1     35.7 MB  phase A: hs_bf+Wt1 | phase B: part | phase C: hfin+Ssum
    //   y_bf   33.5 MB  (own region: pass3 writes while reading Hinit in R1)
    //   z_silu 33.5 MB  bf16 silu(z) from K1 epilogue
    //   Wt6     4.2 MB
    float* ws    = (float*)d_ws;
    float* regA  = ws;
    float* x_bld = regA + (size_t)NROW * 2048;
    float* x_dbl = x_bld + (size_t)NROW * 2048;
    float* R1    = x_dbl + (size_t)NROW * 96;
    float* ybff  = R1 + 8912896;
    float* zbff  = ybff + 8388608;
    float* wt6f  = zbff + 8388608;

    ushort* hs_bf  = (ushort*)R1;
    ushort* Wt1    = (ushort*)(R1 + 4194304);
    float*  part   = R1;
    float*  hfin   = R1;
    float*  Ssum   = R1 + 8388608;
    ushort* y_bf   = (ushort*)ybff;
    ushort* z_silu = (ushort*)zbff;
    ushort* Wt6    = (ushort*)wt6f;

    // C0: converts (hs flat; weights transposed to [N,K] bf16)
    hipLaunchKernelGGL(convert_bf16_flat, dim3(8192), dim3(256), 0, stream,
                       hs, hs_bf, NROW * D_MODEL / 4);
    hipLaunchKernelGGL(transpose_bf16, dim3(4096 / 32, 1024 / 32), dim3(256), 0, stream,
                       in_proj_w, Wt1, 1024, 4096);
    hipLaunchKernelGGL(transpose_bf16, dim3(1024 / 32, 2048 / 32), dim3(256), 0, stream,
                       out_proj_w, Wt6, 2048, 1024);

    // K1: in_proj (bf16 MFMA NT, gload_lds) -> x fp32 (regA) + silu(z) bf16
    hipLaunchKernelGGL((gemm_bf16_nt<1>), dim3(4096 / 128, NROW / 128), dim3(256), 0, stream,
                       hs_bf, Wt1, regA, z_silu, NROW, 4096, D_MODEL, 0);

    // K2: depthwise conv + bias + silu -> x_bld
    {
        const int total = B_SZ * L_SEQ * D_INNER;
        hipLaunchKernelGGL(conv_silu_kernel, dim3((total + 255) / 256), dim3(256), 0, stream,
                           regA, conv_w, conv_b, x_bld);
    }
    // K3: x_dbl = x_bld @ x_proj_w  (split-K fp32)
    {
        hipLaunchKernelGGL(xproj_partial, dim3(NROW / 64, KSPLIT), dim3(256), 0, stream,
                           x_bld, x_proj_w, part);
        hipLaunchKernelGGL(xproj_reduce, dim3(NROW * 96 / 4 / 256), dim3(256), 0, stream,
                           part, x_dbl);
    }
    // K4: delta -> regA (x dead after conv)
    {
        dim3 grid(D_INNER / 256, NROW / 16);
        hipLaunchKernelGGL(dt_softplus_kernel, grid, dim3(256), 0, stream,
                           x_dbl, dt_proj_w, dt_proj_b, regA);
    }
    // K5: chunked scan (thread-local 16-state); pass3 emits bf16 y directly
    {
        const int total1 = B_SZ * D_INNER * NCHUNK;          // 524,288
        hipLaunchKernelGGL(scan_pass1, dim3(total1 / 256), dim3(256), 0, stream,
                           regA, x_bld, x_dbl, A_log, hfin, Ssum);
        const int total2 = B_SZ * D_INNER * D_STATE;         // 131,072
        hipLaunchKernelGGL(scan_pass2, dim3(total2 / 256), dim3(256), 0, stream,
                           hfin, Ssum, A_log);
        hipLaunchKernelGGL(scan_pass3, dim3(total1 / 256), dim3(256), 0, stream,
                           regA, x_bld, z_silu, x_dbl, A_log, D_skip, hfin, y_bf);
    }
    // K6: out = y @ out_proj_w  (bf16 MFMA NT, gload_lds)
    hipLaunchKernelGGL((gemm_bf16_nt<0>), dim3(1024 / 128, NROW / 128), dim3(256), 0, stream,
                       y_bf, Wt6, out, (ushort*)nullptr, NROW, 1024, D_INNER, 1024);
}

// Round 8
// 513.747 us; speedup vs baseline: 6.9542x; 1.0316x over previous
//
#include <hip/hip_runtime.h>

#define B_SZ 4
#define L_SEQ 2048
#define D_MODEL 1024
#define D_INNER 2048
#define D_STATE 16
#define DT_RANK 64
#define NROW (B_SZ * L_SEQ)   // 8192
#define NCHUNK 64
#define CHUNK (L_SEQ / NCHUNK)  // 32
#define KSPLIT 8
#define KCH (D_INNER / KSPLIT)  // 256

typedef __bf16 bf16x8 __attribute__((ext_vector_type(8)));
typedef float  f32x4  __attribute__((ext_vector_type(4)));

__device__ __forceinline__ ushort f2bf(float f) {
    union { float f; uint32_t u; } v; v.f = f;
    const uint32_t r = (v.u + 0x7FFFu + ((v.u >> 16) & 1u)) >> 16;  // RNE
    return (ushort)r;
}
__device__ __forceinline__ float bf2f(ushort u) {
    union { uint32_t u; float f; } v; v.u = ((uint32_t)u) << 16;
    return v.f;
}

// async global->LDS, 16 bytes per lane (dest = wave-uniform base + lane*16)
__device__ __forceinline__ void gload16(const void* g, void* l) {
    __builtin_amdgcn_global_load_lds(
        (const __attribute__((address_space(1))) unsigned int*)g,
        (__attribute__((address_space(3))) unsigned int*)l, 16, 0, 0);
}

// ---------------------------------------------------------------------------
// fp32 -> bf16 flat convert (4 elems/thread)
// ---------------------------------------------------------------------------
__global__ __launch_bounds__(256) void convert_bf16_flat(
    const float* __restrict__ in, ushort* __restrict__ out, int n4)
{
    const int i = blockIdx.x * 256 + threadIdx.x;
    if (i >= n4) return;
    const float4 v = reinterpret_cast<const float4*>(in)[i];
    ushort4 o; o.x = f2bf(v.x); o.y = f2bf(v.y); o.z = f2bf(v.z); o.w = f2bf(v.w);
    reinterpret_cast<ushort4*>(out)[i] = o;
}

// ---------------------------------------------------------------------------
// W[K,N] fp32 -> Wt[N,K] bf16 (32x32 LDS tile transpose)
// ---------------------------------------------------------------------------
__global__ __launch_bounds__(256) void transpose_bf16(
    const float* __restrict__ W, ushort* __restrict__ Wt, int K, int N)
{
    __shared__ float tile[32][33];
    const int n0 = blockIdx.x * 32, k0 = blockIdx.y * 32;
    const int c = threadIdx.x & 31, r = threadIdx.x >> 5;
    #pragma unroll
    for (int p = 0; p < 4; ++p)
        tile[r + p * 8][c] = W[(size_t)(k0 + r + p * 8) * N + n0 + c];
    __syncthreads();
    #pragma unroll
    for (int p = 0; p < 4; ++p)
        Wt[(size_t)(n0 + r + p * 8) * K + k0 + c] = f2bf(tile[c][r + p * 8]);
}

// ---------------------------------------------------------------------------
// bf16 NT GEMM: C[M,N] = A[M,K] * Bt[N,K]^T
// 128x128 tile, BK=64, global_load_lds 16B staging with BOTH-SIDES XOR
// swizzle (rule #21): LDS dest linear, global source chunk pre-permuted by
// chunk ^= row&7, fragment reads apply the same XOR -> 2-way (free) instead
// of the 16-way row-aligned conflict of the plain [128][64] layout.
// EPI=0: plain fp32 C.  EPI=1: in_proj epilogue (x fp32 | silu(z) bf16).
// ---------------------------------------------------------------------------
template <int EPI>
__global__ __launch_bounds__(256) void gemm_bf16_nt(
    const ushort* __restrict__ A, const ushort* __restrict__ Bt,
    float* __restrict__ C, ushort* __restrict__ Cz, int M, int N, int K, int ldc)
{
    __shared__ ushort Alds[128][64];
    __shared__ ushort Blds[128][64];
    const int tid  = threadIdx.x;
    const int lane = tid & 63;
    const int wid  = tid >> 6;
    const int wr = wid >> 1, wc = wid & 1;
    const int m0 = blockIdx.y * 128, n0 = blockIdx.x * 128;
    const int l15 = lane & 15, l16 = lane >> 4;
    const int swz = l15 & 7;                 // read-side XOR key (= row&7)

    f32x4 acc[4][4] = {};

    // staging: thread tid -> LDS row (tid>>3)+32i, chunk (tid&7); global
    // source chunk pre-swizzled so LDS(r,c) = Gchunk(r, c ^ (r&7)).
    const int strow = tid >> 3;
    const int stcol = (((tid & 7) ^ ((tid >> 3) & 7)) * 8);

    for (int k0 = 0; k0 < K; k0 += 64) {
        const ushort* gA = A  + (size_t)(m0 + strow) * K + k0 + stcol;
        const ushort* gB = Bt + (size_t)(n0 + strow) * K + k0 + stcol;
        ushort* lA = &Alds[0][0] + tid * 8;
        ushort* lB = &Blds[0][0] + tid * 8;
        #pragma unroll
        for (int i = 0; i < 4; ++i) {
            gload16(gA + (size_t)i * 32 * K, lA + i * 2048);
            gload16(gB + (size_t)i * 32 * K, lB + i * 2048);
        }
        __syncthreads();  // compiler emits vmcnt(0) drain here
        #pragma unroll
        for (int ks = 0; ks < 64; ks += 32) {
            const int ccb = ks >> 3;         // base chunk: 0 or 4
            bf16x8 af[4], bfr[4];
            #pragma unroll
            for (int mi = 0; mi < 4; ++mi)
                af[mi] = *reinterpret_cast<const bf16x8*>(
                    &Alds[wr * 64 + mi * 16 + l15][((ccb + l16) ^ swz) << 3]);
            #pragma unroll
            for (int ni = 0; ni < 4; ++ni)
                bfr[ni] = *reinterpret_cast<const bf16x8*>(
                    &Blds[wc * 64 + ni * 16 + l15][((ccb + l16) ^ swz) << 3]);
            #pragma unroll
            for (int mi = 0; mi < 4; ++mi)
                #pragma unroll
                for (int ni = 0; ni < 4; ++ni)
                    acc[mi][ni] = __builtin_amdgcn_mfma_f32_16x16x32_bf16(af[mi], bfr[ni], acc[mi][ni], 0, 0, 0);
        }
        __syncthreads();
    }

    #pragma unroll
    for (int mi = 0; mi < 4; ++mi) {
        const int mrow = m0 + wr * 64 + mi * 16 + l16 * 4;
        #pragma unroll
        for (int ni = 0; ni < 4; ++ni) {
            const int ncol = n0 + wc * 64 + ni * 16 + l15;
            #pragma unroll
            for (int r = 0; r < 4; ++r) {
                const float v = acc[mi][ni][r];
                if (EPI == 0) {
                    C[(size_t)(mrow + r) * ldc + ncol] = v;
                } else {
                    if (n0 < 2048) {
                        C[(size_t)(mrow + r) * 2048 + ncol] = v;       // x (fp32)
                    } else {
                        const float s = v / (1.f + __expf(-v));        // silu(z)
                        Cz[(size_t)(mrow + r) * 2048 + (ncol - 2048)] = f2bf(s);
                    }
                }
            }
        }
    }
}

// ---------------------------------------------------------------------------
// K3a: x_proj split-K partial GEMM (N=96, fp32).
// ---------------------------------------------------------------------------
__global__ __launch_bounds__(256) void xproj_partial(
    const float* __restrict__ A, const float* __restrict__ W,
    float* __restrict__ part)
{
    const int m0 = blockIdx.x * 64;
    const int k0 = blockIdx.y * KCH;
    const int tid = threadIdx.x;
    const int tx = tid & 15;
    const int ty = tid >> 4;

    __shared__ float As[16][68];
    __shared__ float Ws[16][96];

    float c[4][6] = {};

    for (int kt = 0; kt < KCH; kt += 16) {
        {
            const int ka = tid & 15, ma = tid >> 4;
            #pragma unroll
            for (int p = 0; p < 4; ++p)
                As[ka][ma + p * 16] = A[(size_t)(m0 + ma + p * 16) * D_INNER + k0 + kt + ka];
        }
        {
            const int kr = tid >> 4;
            const int nc = (tid & 15) * 6;
            #pragma unroll
            for (int j = 0; j < 6; ++j)
                Ws[kr][nc + j] = W[(size_t)(k0 + kt + kr) * 96 + nc + j];
        }
        __syncthreads();
        #pragma unroll
        for (int kk = 0; kk < 16; ++kk) {
            const float4 av = *reinterpret_cast<const float4*>(&As[kk][ty * 4]);
            const float a[4] = {av.x, av.y, av.z, av.w};
            float w[6];
            #pragma unroll
            for (int j = 0; j < 6; ++j) w[j] = Ws[kk][tx * 6 + j];
            #pragma unroll
            for (int i = 0; i < 4; ++i)
                #pragma unroll
                for (int j = 0; j < 6; ++j)
                    c[i][j] = fmaf(a[i], w[j], c[i][j]);
        }
        __syncthreads();
    }

    #pragma unroll
    for (int i = 0; i < 4; ++i) {
        const int m = m0 + ty * 4 + i;
        #pragma unroll
        for (int j = 0; j < 6; ++j)
            part[((size_t)blockIdx.y * NROW + m) * 96 + tx * 6 + j] = c[i][j];
    }
}

__global__ __launch_bounds__(256) void xproj_reduce(
    const float* __restrict__ part, float* __restrict__ x_dbl)
{
    const int i = blockIdx.x * 256 + threadIdx.x;
    if (i >= NROW * 96 / 4) return;
    const float4* p4 = reinterpret_cast<const float4*>(part);
    const size_t stride = (size_t)NROW * 96 / 4;
    float4 s = p4[i];
    #pragma unroll
    for (int ks = 1; ks < KSPLIT; ++ks) {
        const float4 v = p4[(size_t)ks * stride + i];
        s.x += v.x; s.y += v.y; s.z += v.z; s.w += v.w;
    }
    reinterpret_cast<float4*>(x_dbl)[i] = s;
}

// ---------------------------------------------------------------------------
// Depthwise conv (taps x[t-6..t-3]) + bias + SiLU.  x is [NROW][2048] fp32.
// ---------------------------------------------------------------------------
__global__ __launch_bounds__(256) void conv_silu_kernel(
    const float* __restrict__ x, const float* __restrict__ conv_w,
    const float* __restrict__ conv_b, float* __restrict__ x_bld)
{
    const int idx = blockIdx.x * 256 + threadIdx.x;
    if (idx >= B_SZ * L_SEQ * D_INNER) return;
    const int d = idx & (D_INNER - 1);
    const int t = (idx >> 11) & (L_SEQ - 1);
    const int b = idx >> 22;

    const float4 w = *reinterpret_cast<const float4*>(&conv_w[d * 4]);
    const float wk[4] = {w.x, w.y, w.z, w.w};
    float acc = conv_b[d];
    const size_t rowbase = (size_t)b * L_SEQ * D_INNER + d;
    #pragma unroll
    for (int k = 0; k < 4; ++k) {
        const int tt = t - 6 + k;
        if (tt >= 0) acc = fmaf(wk[k], x[rowbase + (size_t)tt * D_INNER], acc);
    }
    const float s = acc / (1.f + __expf(-acc));
    x_bld[idx] = s;
}

// ---------------------------------------------------------------------------
// delta = softplus(dt_low @ dt_proj_w + 2*bias) -> delta[M][2048]
// ---------------------------------------------------------------------------
__global__ __launch_bounds__(256) void dt_softplus_kernel(
    const float* __restrict__ x_dbl, const float* __restrict__ W,
    const float* __restrict__ bias, float* __restrict__ delta)
{
    __shared__ float a[16][64];
    const int tid = threadIdx.x;
    const int m0 = blockIdx.y * 16;
    const int d = blockIdx.x * 256 + tid;

    {
        const int r = tid & 63, i = tid >> 6;
        #pragma unroll
        for (int p = 0; p < 4; ++p)
            a[i + p * 4][r] = x_dbl[(size_t)(m0 + i + p * 4) * 96 + r];
    }
    __syncthreads();

    float acc[16] = {};
    for (int r = 0; r < 64; ++r) {
        const float w = W[(size_t)r * D_INNER + d];
        #pragma unroll
        for (int mi = 0; mi < 16; ++mi) acc[mi] = fmaf(a[mi][r], w, acc[mi]);
    }
    const float b2 = 2.0f * bias[d];
    #pragma unroll
    for (int mi = 0; mi < 16; ++mi) {
        const float v = acc[mi] + b2;
        const float sp = (v > 20.0f) ? v : log1pf(__expf(v));
        delta[(size_t)(m0 + mi) * D_INNER + d] = sp;
    }
}

// ---------------------------------------------------------------------------
// Chunked parallel scan, thread-local 16-state (see round 4/5 notes).
// ---------------------------------------------------------------------------
__global__ __launch_bounds__(256) void scan_pass1(
    const float* __restrict__ delta, const float* __restrict__ u_,
    const float* __restrict__ x_dbl, const float* __restrict__ A_log,
    float* __restrict__ hfin, float* __restrict__ Ssum)
{
    const int g = blockIdx.x * 256 + threadIdx.x;  // 0 .. 524287
    const int d = g & (D_INNER - 1);
    const int b = (g >> 11) & 3;
    const int c = g >> 13;

    float A[D_STATE];
    #pragma unroll
    for (int q = 0; q < 4; ++q) {
        const float4 al = *reinterpret_cast<const float4*>(&A_log[d * D_STATE + q * 4]);
        A[q * 4 + 0] = -__expf(al.x); A[q * 4 + 1] = -__expf(al.y);
        A[q * 4 + 2] = -__expf(al.z); A[q * 4 + 3] = -__expf(al.w);
    }

    const int t0 = c * CHUNK;
    const size_t base2048 = (size_t)b * L_SEQ * D_INNER + d;
    const size_t base96   = (size_t)b * L_SEQ * 96;

    float h[D_STATE] = {};
    float S = 0.f;
    for (int i = 0; i < CHUNK; ++i) {
        const int t = t0 + i;
        const float dv = delta[base2048 + (size_t)t * D_INNER];
        const float uv = u_[base2048 + (size_t)t * D_INNER];
        float Bv[D_STATE];
        #pragma unroll
        for (int q = 0; q < 4; ++q)
            *reinterpret_cast<float4*>(&Bv[q * 4]) =
                *reinterpret_cast<const float4*>(&x_dbl[base96 + (size_t)t * 96 + DT_RANK + q * 4]);
        const float du = dv * uv;
        S += dv;
        #pragma unroll
        for (int n = 0; n < D_STATE; ++n)
            h[n] = fmaf(h[n], __expf(dv * A[n]), du * Bv[n]);
    }
    const size_t sidx = (size_t)(c * B_SZ + b) * D_INNER + d;
    #pragma unroll
    for (int q = 0; q < 4; ++q)
        *reinterpret_cast<float4*>(&hfin[sidx * D_STATE + q * 4]) =
            *reinterpret_cast<const float4*>(&h[q * 4]);
    Ssum[sidx] = S;
}

__global__ __launch_bounds__(256) void scan_pass2(
    float* __restrict__ hfin, const float* __restrict__ Ssum,
    const float* __restrict__ A_log)
{
    const int g = blockIdx.x * 256 + threadIdx.x;  // 0 .. 131071
    const int n = g & 15;
    const int d = (g >> 4) & (D_INNER - 1);
    const int b = g >> 15;
    const float A = -__expf(A_log[d * D_STATE + n]);

    float H = 0.f;
    #pragma unroll 4
    for (int c = 0; c < NCHUNK; ++c) {
        const size_t sidx = (size_t)(c * B_SZ + b) * D_INNER + d;
        const float P = __expf(A * Ssum[sidx]);
        const float hc = hfin[sidx * D_STATE + n];
        hfin[sidx * D_STATE + n] = H;       // Hinit in place
        H = fmaf(H, P, hc);
    }
}

__global__ __launch_bounds__(256) void scan_pass3(
    const float* __restrict__ delta, const float* __restrict__ u_,
    const ushort* __restrict__ z_silu, const float* __restrict__ x_dbl,
    const float* __restrict__ A_log, const float* __restrict__ D_skip,
    const float* __restrict__ Hinit, ushort* __restrict__ y_bf)
{
    const int g = blockIdx.x * 256 + threadIdx.x;  // 0 .. 524287
    const int d = g & (D_INNER - 1);
    const int b = (g >> 11) & 3;
    const int c = g >> 13;

    float A[D_STATE];
    #pragma unroll
    for (int q = 0; q < 4; ++q) {
        const float4 al = *reinterpret_cast<const float4*>(&A_log[d * D_STATE + q * 4]);
        A[q * 4 + 0] = -__expf(al.x); A[q * 4 + 1] = -__expf(al.y);
        A[q * 4 + 2] = -__expf(al.z); A[q * 4 + 3] = -__expf(al.w);
    }
    const float Dd = D_skip[d];

    const int t0 = c * CHUNK;
    const size_t base2048 = (size_t)b * L_SEQ * D_INNER + d;
    const size_t base96   = (size_t)b * L_SEQ * 96;

    float h[D_STATE];
    const size_t sidx = (size_t)(c * B_SZ + b) * D_INNER + d;
    #pragma unroll
    for (int q = 0; q < 4; ++q)
        *reinterpret_cast<float4*>(&h[q * 4]) =
            *reinterpret_cast<const float4*>(&Hinit[sidx * D_STATE + q * 4]);

    for (int i = 0; i < CHUNK; ++i) {
        const int t = t0 + i;
        const size_t off = base2048 + (size_t)t * D_INNER;
        const float dv = delta[off];
        const float uv = u_[off];
        const float zs = bf2f(z_silu[off]);
        float Bv[D_STATE], Cv[D_STATE];
        #pragma unroll
        for (int q = 0; q < 4; ++q) {
            *reinterpret_cast<float4*>(&Bv[q * 4]) =
                *reinterpret_cast<const float4*>(&x_dbl[base96 + (size_t)t * 96 + DT_RANK + q * 4]);
            *reinterpret_cast<float4*>(&Cv[q * 4]) =
                *reinterpret_cast<const float4*>(&x_dbl[base96 + (size_t)t * 96 + DT_RANK + D_STATE + q * 4]);
        }
        const float du = dv * uv;
        float y = 0.f;
        #pragma unroll
        for (int n = 0; n < D_STATE; ++n) {
            h[n] = fmaf(h[n], __expf(dv * A[n]), du * Bv[n]);
            y = fmaf(h[n], Cv[n], y);
        }
        const float yv = (y + uv * Dd) * zs;
        y_bf[off] = f2bf(yv);
    }
}

// ---------------------------------------------------------------------------
extern "C" void kernel_launch(void* const* d_in, const int* in_sizes, int n_in,
                              void* d_out, int out_size, void* d_ws, size_t ws_size,
                              hipStream_t stream)
{
    const float* hs         = (const float*)d_in[0];
    const float* in_proj_w  = (const float*)d_in[1];
    const float* conv_w     = (const float*)d_in[2];
    const float* conv_b     = (const float*)d_in[3];
    const float* x_proj_w   = (const float*)d_in[4];
    const float* dt_proj_w  = (const float*)d_in[5];
    const float* dt_proj_b  = (const float*)d_in[6];
    const float* A_log      = (const float*)d_in[7];
    const float* D_skip     = (const float*)d_in[8];
    const float* out_proj_w = (const float*)d_in[9];
    float* out = (float*)d_out;

    // Workspace (f32 elems), total 244.3 MB (known-good size):
    //   regA   67.1 MB  x_f32 [8192][2048] -> (dead after conv) delta
    //   x_bld  67.1 MB
    //   x_dbl   3.1 MB
    //   R1     35.7 MB  phase A: hs_bf+Wt1 | phase B: part | phase C: hfin+Ssum
    //   y_bf   33.5 MB
    //   z_silu 33.5 MB
    //   Wt6     4.2 MB
    float* ws    = (float*)d_ws;
    float* regA  = ws;
    float* x_bld = regA + (size_t)NROW * 2048;
    float* x_dbl = x_bld + (size_t)NROW * 2048;
    float* R1    = x_dbl + (size_t)NROW * 96;
    float* ybff  = R1 + 8912896;
    float* zbff  = ybff + 8388608;
    float* wt6f  = zbff + 8388608;

    ushort* hs_bf  = (ushort*)R1;
    ushort* Wt1    = (ushort*)(R1 + 4194304);
    float*  part   = R1;
    float*  hfin   = R1;
    float*  Ssum   = R1 + 8388608;
    ushort* y_bf   = (ushort*)ybff;
    ushort* z_silu = (ushort*)zbff;
    ushort* Wt6    = (ushort*)wt6f;

    // C0: converts (hs flat; weights transposed to [N,K] bf16)
    hipLaunchKernelGGL(convert_bf16_flat, dim3(8192), dim3(256), 0, stream,
                       hs, hs_bf, NROW * D_MODEL / 4);
    hipLaunchKernelGGL(transpose_bf16, dim3(4096 / 32, 1024 / 32), dim3(256), 0, stream,
                       in_proj_w, Wt1, 1024, 4096);
    hipLaunchKernelGGL(transpose_bf16, dim3(1024 / 32, 2048 / 32), dim3(256), 0, stream,
                       out_proj_w, Wt6, 2048, 1024);

    // K1: in_proj (bf16 MFMA NT, swizzled gload_lds) -> x fp32 + silu(z) bf16
    hipLaunchKernelGGL((gemm_bf16_nt<1>), dim3(4096 / 128, NROW / 128), dim3(256), 0, stream,
                       hs_bf, Wt1, regA, z_silu, NROW, 4096, D_MODEL, 0);

    // K2: depthwise conv + bias + silu -> x_bld
    {
        const int total = B_SZ * L_SEQ * D_INNER;
        hipLaunchKernelGGL(conv_silu_kernel, dim3((total + 255) / 256), dim3(256), 0, stream,
                           regA, conv_w, conv_b, x_bld);
    }
    // K3: x_dbl = x_bld @ x_proj_w  (split-K fp32)
    {
        hipLaunchKernelGGL(xproj_partial, dim3(NROW / 64, KSPLIT), dim3(256), 0, stream,
                           x_bld, x_proj_w, part);
        hipLaunchKernelGGL(xproj_reduce, dim3(NROW * 96 / 4 / 256), dim3(256), 0, stream,
                           part, x_dbl);
    }
    // K4: delta -> regA (x dead after conv)
    {
        dim3 grid(D_INNER / 256, NROW / 16);
        hipLaunchKernelGGL(dt_softplus_kernel, grid, dim3(256), 0, stream,
                           x_dbl, dt_proj_w, dt_proj_b, regA);
    }
    // K5: chunked scan (thread-local 16-state); pass3 emits bf16 y directly
    {
        const int total1 = B_SZ * D_INNER * NCHUNK;          // 524,288
        hipLaunchKernelGGL(scan_pass1, dim3(total1 / 256), dim3(256), 0, stream,
                           regA, x_bld, x_dbl, A_log, hfin, Ssum);
        const int total2 = B_SZ * D_INNER * D_STATE;         // 131,072
        hipLaunchKernelGGL(scan_pass2, dim3(total2 / 256), dim3(256), 0, stream,
                           hfin, Ssum, A_log);
        hipLaunchKernelGGL(scan_pass3, dim3(total1 / 256), dim3(256), 0, stream,
                           regA, x_bld, z_silu, x_dbl, A_log, D_skip, hfin, y_bf);
    }
    // K6: out = y @ out_proj_w  (bf16 MFMA NT, swizzled gload_lds)
    hipLaunchKernelGGL((gemm_bf16_nt<0>), dim3(1024 / 128, NROW / 128), dim3(256), 0, stream,
                       y_bf, Wt6, out, (ushort*)nullptr, NROW, 1024, D_INNER, 1024);
}